// Round 1
// baseline (7868.159 us; speedup 1.0000x reference)
//
#include <hip/hip_runtime.h>
#include <math.h>

#define HID   64
#define HEADS 4
#define DH    16
#define NU    30000
#define NE_   60000
#define NV    1000
#define NTOT  91000
#define ETOT  870000
#define LAYERS 2

// Edge-type tables
__device__ const int d_EOFF[14] = {0,150000,270000,330000,370000,400000,450000,
                                   570000,630000,670000,700000,750000,810000,870000};
__device__ const int d_ECNT[13] = {150000,120000,60000,40000,30000,50000,
                                   120000,60000,40000,30000,50000,60000,60000};
__device__ const int d_EST[13]  = {0,0,0,0,0,0,1,1,1,1,1,1,2};
__device__ const int d_EDT[13]  = {0,1,1,1,1,1,0,0,0,0,0,2,1};
__device__ const int d_NOFF[3]  = {0, NU, NU + NE_};

struct EdgePtrs { const int* p[13]; };

__device__ __forceinline__ unsigned enc_f(float f) {
    unsigned b = __float_as_uint(f);
    return (b & 0x80000000u) ? ~b : (b | 0x80000000u);
}
__device__ __forceinline__ float dec_f(unsigned u) {
    unsigned b = (u & 0x80000000u) ? (u & 0x7FFFFFFFu) : ~u;
    return __uint_as_float(b);
}
__device__ __forceinline__ int node_type(int n) {
    return (n >= NU) + (n >= NU + NE_);
}

// ---------------- input projection: h = x@W + b + emb[ids] ----------------
__global__ void k_init(const float* __restrict__ xu, const float* __restrict__ xe,
                       const float* __restrict__ xv,
                       const float* __restrict__ Wu, const float* __restrict__ bu,
                       const float* __restrict__ We, const float* __restrict__ be,
                       const float* __restrict__ Wv_, const float* __restrict__ bv,
                       const float* __restrict__ embu, const float* __restrict__ embe,
                       const float* __restrict__ embv,
                       const int* __restrict__ idu, const int* __restrict__ ide,
                       const int* __restrict__ idv,
                       float* __restrict__ h) {
    int gid = blockIdx.x * blockDim.x + threadIdx.x;
    if (gid >= NTOT * HID) return;
    int node = gid >> 6, j = gid & 63;
    const float *x, *W, *b, *emb; const int* ids; int in_dim, n;
    if (node < NU)            { n = node;           x = xu; W = Wu;  b = bu; emb = embu; ids = idu; in_dim = 32; }
    else if (node < NU + NE_) { n = node - NU;      x = xe; W = We;  b = be; emb = embe; ids = ide; in_dim = 32; }
    else                      { n = node - NU - NE_;x = xv; W = Wv_; b = bv; emb = embv; ids = idv; in_dim = 16; }
    float acc = b[j] + emb[(size_t)ids[n] * HID + j];
    for (int i = 0; i < in_dim; i++) acc += x[(size_t)n * in_dim + i] * W[i * HID + j];
    h[gid] = acc;
}

// ---------------- kqv = h@Wkqv + bkqv (per node; 192 outputs) ----------------
__global__ void k_kqv(const float* __restrict__ h, const float* __restrict__ Wkqv,
                      const float* __restrict__ bkqv, float* __restrict__ kqv, int layer) {
    int node = blockIdx.x, j = threadIdx.x;   // j in [0,192)
    __shared__ float hs[HID];
    if (j < HID) hs[j] = h[(size_t)node * HID + j];
    __syncthreads();
    int t = node_type(node);
    const float* W = Wkqv + (size_t)(layer * 3 + t) * HID * 192;
    float acc = bkqv[(layer * 3 + t) * 192 + j];
    #pragma unroll 16
    for (int i = 0; i < HID; i++) acc += hs[i] * W[i * 192 + j];
    kqv[(size_t)node * 192 + j] = acc;
}

// ---------------- pass 1: per-(edge,head) score + segment max ----------------
__global__ void k_score(const float* __restrict__ kqv, const float* __restrict__ Wk,
                        const float* __restrict__ p_rel, float* __restrict__ sc,
                        unsigned* __restrict__ smax, EdgePtrs ep, int layer) {
    int gid = blockIdx.x * blockDim.x + threadIdx.x;
    if (gid >= ETOT * HEADS) return;
    int eh = gid & 3, eidx = gid >> 2;
    int e = 0;
    #pragma unroll
    for (int i = 1; i < 13; i++) e += (eidx >= d_EOFF[i]);
    int li = eidx - d_EOFF[e];
    const int* base = ep.p[e];
    int src = base[li], dst = base[d_ECNT[e] + li];
    int sg = d_NOFF[d_EST[e]] + src;
    int dg = d_NOFF[d_EDT[e]] + dst;
    const float* kk = kqv + (size_t)sg * 192 + eh * DH;
    const float* qq = kqv + (size_t)dg * 192 + 64 + eh * DH;
    const float* W  = Wk + ((size_t)(layer * 13 + e) * HEADS + eh) * DH * DH;
    float kr[DH], qr[DH];
    #pragma unroll
    for (int i = 0; i < DH; i++) { kr[i] = kk[i]; qr[i] = qq[i]; }
    float s = 0.f;
    #pragma unroll
    for (int x = 0; x < DH; x++) {
        float ke = 0.f;
        #pragma unroll
        for (int d = 0; d < DH; d++) ke += kr[d] * W[d * DH + x];
        s += qr[x] * ke;
    }
    s *= p_rel[(layer * 13 + e) * HEADS + eh] * 0.25f;   // scale = 1/sqrt(16)
    sc[gid] = s;
    atomicMax(&smax[(size_t)dg * HEADS + eh], enc_f(s));
}

// ---------------- pass 2: exp, denominator, numerator (ex * ve) ----------------
__global__ void k_expagg(const float* __restrict__ kqv, const float* __restrict__ Wv,
                         const float* __restrict__ sc, const unsigned* __restrict__ smax,
                         float* __restrict__ den, float* __restrict__ num,
                         EdgePtrs ep, int layer) {
    int gid = blockIdx.x * blockDim.x + threadIdx.x;
    if (gid >= ETOT * HEADS) return;
    int eh = gid & 3, eidx = gid >> 2;
    int e = 0;
    #pragma unroll
    for (int i = 1; i < 13; i++) e += (eidx >= d_EOFF[i]);
    int li = eidx - d_EOFF[e];
    const int* base = ep.p[e];
    int src = base[li], dst = base[d_ECNT[e] + li];
    int sg = d_NOFF[d_EST[e]] + src;
    int dg = d_NOFF[d_EDT[e]] + dst;
    float mx = dec_f(smax[(size_t)dg * HEADS + eh]);
    float ex = expf(sc[gid] - mx);
    atomicAdd(&den[(size_t)dg * HEADS + eh], ex);
    const float* vv = kqv + (size_t)sg * 192 + 128 + eh * DH;
    const float* W  = Wv + ((size_t)(layer * 13 + e) * HEADS + eh) * DH * DH;
    float vr[DH];
    #pragma unroll
    for (int i = 0; i < DH; i++) vr[i] = vv[i];
    #pragma unroll
    for (int x = 0; x < DH; x++) {
        float ve = 0.f;
        #pragma unroll
        for (int d = 0; d < DH; d++) ve += vr[d] * W[d * DH + x];
        atomicAdd(&num[(size_t)dg * HID + eh * DH + x], ex * ve);
    }
}

// ---------------- epilogue: agg -> gelu -> @Wout + bout -> skip-gate -> relu ----------------
__global__ void k_out(const float* __restrict__ num, const float* __restrict__ den,
                      const float* __restrict__ Wout, const float* __restrict__ bout,
                      const float* __restrict__ skip, float* __restrict__ h, int layer) {
    int node = blockIdx.x, j = threadIdx.x;   // 64 threads
    int t = node_type(node);
    __shared__ float gs[HID];
    float d = den[(size_t)node * HEADS + (j >> 4)];
    float o = (d > 0.f) ? num[(size_t)node * HID + j] / d : 0.f;
    float ge = 0.5f * o * (1.f + erff(o * 0.70710678118654752f));
    gs[j] = ge;
    __syncthreads();
    const float* W = Wout + (size_t)(layer * 3 + t) * HID * HID;
    float a = bout[(layer * 3 + t) * HID + j];
    #pragma unroll 16
    for (int i = 0; i < HID; i++) a += gs[i] * W[i * HID + j];
    float g = 1.f / (1.f + expf(-skip[layer * 3 + t]));
    float r = g * a + (1.f - g) * h[(size_t)node * HID + j];
    h[(size_t)node * HID + j] = fmaxf(r, 0.f);   // relu after each layer
}

// ---------------- final l2 normalize ----------------
__global__ void k_l2(const float* __restrict__ h, float* __restrict__ out) {
    int node = blockIdx.x, j = threadIdx.x;   // 64 = one wave
    float v = h[(size_t)node * HID + j];
    float ss = v * v;
    #pragma unroll
    for (int off = 32; off > 0; off >>= 1) ss += __shfl_down(ss, off);
    ss = __shfl(ss, 0);
    float nrm = fmaxf(sqrtf(ss), 1e-12f);
    out[(size_t)node * HID + j] = v / nrm;
}

extern "C" void kernel_launch(void* const* d_in, const int* in_sizes, int n_in,
                              void* d_out, int out_size, void* d_ws, size_t ws_size,
                              hipStream_t stream) {
    const float* xu   = (const float*)d_in[0];
    const float* xe   = (const float*)d_in[1];
    const float* xv   = (const float*)d_in[2];
    const float* Wu   = (const float*)d_in[3];
    const float* bu   = (const float*)d_in[4];
    const float* We   = (const float*)d_in[5];
    const float* be   = (const float*)d_in[6];
    const float* Wv_  = (const float*)d_in[7];
    const float* bv   = (const float*)d_in[8];
    const float* embu = (const float*)d_in[9];
    const float* embe = (const float*)d_in[10];
    const float* embv = (const float*)d_in[11];
    const float* Wkqv = (const float*)d_in[12];
    const float* bkqv = (const float*)d_in[13];
    const float* Wk   = (const float*)d_in[14];
    const float* Wv   = (const float*)d_in[15];
    const float* prel = (const float*)d_in[16];
    const float* Wout = (const float*)d_in[17];
    const float* bout = (const float*)d_in[18];
    const float* skip = (const float*)d_in[19];
    const int*   idu  = (const int*)d_in[20];
    const int*   ide  = (const int*)d_in[21];
    const int*   idv  = (const int*)d_in[22];
    EdgePtrs ep;
    for (int e = 0; e < 13; e++) ep.p[e] = (const int*)d_in[23 + e];

    float* ws  = (float*)d_ws;
    float* h   = ws;                                  // NTOT*64
    float* kqv = h   + (size_t)NTOT * HID;            // NTOT*192
    float* sc  = kqv + (size_t)NTOT * 192;            // ETOT*4
    unsigned* smax = (unsigned*)(sc + (size_t)ETOT * HEADS);   // NTOT*4
    float* den = (float*)(smax + (size_t)NTOT * HEADS);        // NTOT*4
    float* num = den + (size_t)NTOT * HEADS;                   // NTOT*64

    k_init<<<(NTOT * HID + 255) / 256, 256, 0, stream>>>(
        xu, xe, xv, Wu, bu, We, be, Wv_, bv, embu, embe, embv, idu, ide, idv, h);

    for (int l = 0; l < LAYERS; l++) {
        k_kqv<<<NTOT, 192, 0, stream>>>(h, Wkqv, bkqv, kqv, l);
        // zero smax+den+num (contiguous): NTOT*(4+4+64) elems
        hipMemsetAsync(smax, 0, (size_t)NTOT * (HEADS + HEADS + HID) * 4, stream);
        int eth = ETOT * HEADS;
        k_score<<<(eth + 255) / 256, 256, 0, stream>>>(kqv, Wk, prel, sc, smax, ep, l);
        k_expagg<<<(eth + 255) / 256, 256, 0, stream>>>(kqv, Wv, sc, smax, den, num, ep, l);
        k_out<<<NTOT, HID, 0, stream>>>(num, den, Wout, bout, skip, h, l);
    }
    k_l2<<<NTOT, HID, 0, stream>>>(h, (float*)d_out);
}

// Round 2
// 2055.782 us; speedup vs baseline: 3.8273x; 3.8273x over previous
//
#include <hip/hip_runtime.h>
#include <math.h>

#define HID   64
#define HEADS 4
#define DH    16
#define NU    30000
#define NE_   60000
#define NV    1000
#define NTOT  91000
#define ETOT  870000
#define LAYERS 2

// Edge-type tables
__device__ const int d_EOFF[14] = {0,150000,270000,330000,370000,400000,450000,
                                   570000,630000,670000,700000,750000,810000,870000};
__device__ const int d_ECNT[13] = {150000,120000,60000,40000,30000,50000,
                                   120000,60000,40000,30000,50000,60000,60000};
__device__ const int d_EST[13]  = {0,0,0,0,0,0,1,1,1,1,1,1,2};
__device__ const int d_EDT[13]  = {0,1,1,1,1,1,0,0,0,0,0,2,1};
__device__ const int d_NOFF[3]  = {0, NU, NU + NE_};

struct EdgePtrs { const int* p[13]; };

__device__ __forceinline__ int node_type(int n) {
    return (n >= NU) + (n >= NU + NE_);
}

// ---------------- input projection: h = x@W + b + emb[ids] ----------------
__global__ void k_init(const float* __restrict__ xu, const float* __restrict__ xe,
                       const float* __restrict__ xv,
                       const float* __restrict__ Wu, const float* __restrict__ bu,
                       const float* __restrict__ We, const float* __restrict__ be,
                       const float* __restrict__ Wv_, const float* __restrict__ bv,
                       const float* __restrict__ embu, const float* __restrict__ embe,
                       const float* __restrict__ embv,
                       const int* __restrict__ idu, const int* __restrict__ ide,
                       const int* __restrict__ idv,
                       float* __restrict__ h) {
    int gid = blockIdx.x * blockDim.x + threadIdx.x;
    if (gid >= NTOT * HID) return;
    int node = gid >> 6, j = gid & 63;
    const float *x, *W, *b, *emb; const int* ids; int in_dim, n;
    if (node < NU)            { n = node;           x = xu; W = Wu;  b = bu; emb = embu; ids = idu; in_dim = 32; }
    else if (node < NU + NE_) { n = node - NU;      x = xe; W = We;  b = be; emb = embe; ids = ide; in_dim = 32; }
    else                      { n = node - NU - NE_;x = xv; W = Wv_; b = bv; emb = embv; ids = idv; in_dim = 16; }
    float acc = b[j] + emb[(size_t)ids[n] * HID + j];
    for (int i = 0; i < in_dim; i++) acc += x[(size_t)n * in_dim + i] * W[i * HID + j];
    h[gid] = acc;
}

// ---------------- CSR build ----------------
__global__ void k_cnt(EdgePtrs ep, int* __restrict__ cnt) {
    int eidx = blockIdx.x * blockDim.x + threadIdx.x;
    if (eidx >= ETOT) return;
    int e = 0;
    #pragma unroll
    for (int i = 1; i < 13; i++) e += (eidx >= d_EOFF[i]);
    int li = eidx - d_EOFF[e];
    int dst = ep.p[e][d_ECNT[e] + li];
    atomicAdd(&cnt[d_NOFF[d_EDT[e]] + dst], 1);
}

__global__ void k_scan_a(const int* __restrict__ cnt, int* __restrict__ partial) {
    __shared__ int s[256];
    int i = blockIdx.x * 256 + threadIdx.x;
    s[threadIdx.x] = (i < NTOT) ? cnt[i] : 0;
    __syncthreads();
    for (int off = 128; off > 0; off >>= 1) {
        if (threadIdx.x < off) s[threadIdx.x] += s[threadIdx.x + off];
        __syncthreads();
    }
    if (threadIdx.x == 0) partial[blockIdx.x] = s[0];
}

__global__ void k_scan_b(int* __restrict__ partial, int nblk) {
    __shared__ int s[512];
    int t = threadIdx.x;
    s[t] = (t < nblk) ? partial[t] : 0;
    __syncthreads();
    for (int off = 1; off < 512; off <<= 1) {
        int v = (t >= off) ? s[t - off] : 0;
        __syncthreads();
        s[t] += v;
        __syncthreads();
    }
    if (t < nblk) partial[t] = t ? s[t - 1] : 0;   // exclusive
}

__global__ void k_scan_c(const int* __restrict__ cnt, const int* __restrict__ partial,
                         int* __restrict__ row_ptr) {
    __shared__ int s[256];
    int i = blockIdx.x * 256 + threadIdx.x, t = threadIdx.x;
    int v = (i < NTOT) ? cnt[i] : 0;
    s[t] = v;
    __syncthreads();
    for (int off = 1; off < 256; off <<= 1) {
        int u = (t >= off) ? s[t - off] : 0;
        __syncthreads();
        s[t] += u;
        __syncthreads();
    }
    if (i < NTOT) row_ptr[i] = s[t] - v + partial[blockIdx.x];
    if (i == NTOT - 1) row_ptr[NTOT] = ETOT;
}

__global__ void k_fill(EdgePtrs ep, const int* __restrict__ row_ptr,
                       int* __restrict__ cursor, int2* __restrict__ csr) {
    int eidx = blockIdx.x * blockDim.x + threadIdx.x;
    if (eidx >= ETOT) return;
    int e = 0;
    #pragma unroll
    for (int i = 1; i < 13; i++) e += (eidx >= d_EOFF[i]);
    int li = eidx - d_EOFF[e];
    const int* base = ep.p[e];
    int src = base[li], dst = base[d_ECNT[e] + li];
    int sg = d_NOFF[d_EST[e]] + src;
    int dg = d_NOFF[d_EDT[e]] + dst;
    int pos = atomicAdd(&cursor[dg], 1);
    csr[row_ptr[dg] + pos] = make_int2(eidx, sg | (e << 17));
}

// ---------------- kqv = h@Wkqv + bkqv : 8 nodes/block for W reuse ----------------
__global__ void k_kqv(const float* __restrict__ h, const float* __restrict__ Wkqv,
                      const float* __restrict__ bkqv, float* __restrict__ kqv, int layer) {
    int n0 = blockIdx.x * 8;
    int t = node_type(n0);          // 8-node tiles never straddle type boundaries
    __shared__ float hs[8][64];
    for (int i = threadIdx.x; i < 512; i += 192)
        hs[i >> 6][i & 63] = h[(size_t)n0 * 64 + i];
    __syncthreads();
    const float* W = Wkqv + (size_t)(layer * 3 + t) * HID * 192;
    int j = threadIdx.x;
    float b = bkqv[(layer * 3 + t) * 192 + j];
    float acc[8];
    #pragma unroll
    for (int n = 0; n < 8; n++) acc[n] = b;
    for (int i = 0; i < 64; i++) {
        float w = W[i * 192 + j];
        #pragma unroll
        for (int n = 0; n < 8; n++) acc[n] += hs[n][i] * w;
    }
    #pragma unroll
    for (int n = 0; n < 8; n++) kqv[(size_t)(n0 + n) * 192 + j] = acc[n];
}

// ---------------- scores (edge-parallel, no atomics) ----------------
__global__ void k_score(const float* __restrict__ kqv, const float* __restrict__ Wk,
                        const float* __restrict__ p_rel, float* __restrict__ sc,
                        EdgePtrs ep, int layer) {
    int gid = blockIdx.x * blockDim.x + threadIdx.x;
    if (gid >= ETOT * HEADS) return;
    int eh = gid & 3, eidx = gid >> 2;
    int e = 0;
    #pragma unroll
    for (int i = 1; i < 13; i++) e += (eidx >= d_EOFF[i]);
    int li = eidx - d_EOFF[e];
    const int* base = ep.p[e];
    int src = base[li], dst = base[d_ECNT[e] + li];
    int sg = d_NOFF[d_EST[e]] + src;
    int dg = d_NOFF[d_EDT[e]] + dst;
    const float4* kp = (const float4*)(kqv + (size_t)sg * 192 + eh * DH);
    const float4* qp = (const float4*)(kqv + (size_t)dg * 192 + 64 + eh * DH);
    float kr[DH], qr[DH];
    #pragma unroll
    for (int i = 0; i < 4; i++) { ((float4*)kr)[i] = kp[i]; ((float4*)qr)[i] = qp[i]; }
    const float* W = Wk + ((size_t)(layer * 13 + e) * HEADS + eh) * DH * DH;
    float s = 0.f;
    #pragma unroll
    for (int x = 0; x < DH; x++) {
        float ke = 0.f;
        #pragma unroll
        for (int d = 0; d < DH; d++) ke += kr[d] * W[d * DH + x];
        s += qr[x] * ke;
    }
    s *= p_rel[(layer * 13 + e) * HEADS + eh] * 0.25f;   // 1/sqrt(16)
    sc[gid] = s;
}

// ---------------- gather: per-dst online softmax + message agg (no atomics) ----------------
#define WVSTRIDE 264   // 256 + 8: head groups land 8 banks apart -> 2-way (free)
__global__ __launch_bounds__(512)
void k_gather(const float* __restrict__ kqv, const float* __restrict__ sc,
              const float* __restrict__ Wv, const int* __restrict__ row_ptr,
              const int2* __restrict__ csr, float* __restrict__ agg, int layer) {
    __shared__ float wv[13 * 4 * WVSTRIDE];
    for (int i = threadIdx.x; i < 13 * 4 * 256; i += 512) {
        int g = i >> 8, r = i & 255;
        wv[g * WVSTRIDE + r] = Wv[(size_t)layer * 13312 + i];
    }
    __syncthreads();
    int wave = threadIdx.x >> 6, lane = threadIdx.x & 63;
    int node = blockIdx.x * 8 + wave;
    if (node >= NTOT) return;
    int h = lane >> 4, x = lane & 15;
    int beg = row_ptr[node], end = row_ptr[node + 1];
    float m = -1e30f, l = 0.f, acc = 0.f;
    for (int i = beg; i < end; i++) {
        int2 c = csr[i];
        int eidx = c.x, sg = c.y & 0x1FFFF, e = c.y >> 17;
        float s  = sc[eidx * 4 + h];
        float vd = kqv[(size_t)sg * 192 + 128 + lane];   // 256B coalesced gather
        const float* wbase = &wv[(e * 4 + h) * WVSTRIDE + x];
        float ve = 0.f;
        #pragma unroll
        for (int d = 0; d < 16; d++) {
            float vdd = __shfl(vd, (lane & 48) + d, 64);
            ve += vdd * wbase[d * 16];
        }
        float m2  = fmaxf(m, s);
        float sc1 = __expf(m - m2);
        float es  = __expf(s - m2);
        l   = l * sc1 + es;
        acc = acc * sc1 + es * ve;
        m = m2;
    }
    agg[(size_t)node * 64 + lane] = (l > 0.f) ? acc / l : 0.f;
}

// ---------------- epilogue: gelu -> @Wout + bout -> skip-gate -> relu ----------------
__global__ void k_out(const float* __restrict__ agg, const float* __restrict__ Wout,
                      const float* __restrict__ bout, const float* __restrict__ skip,
                      float* __restrict__ h, int layer) {
    int n0 = blockIdx.x * 8;
    int t = node_type(n0);
    int j = threadIdx.x;                 // 64 threads
    __shared__ float gs[8][64];
    #pragma unroll
    for (int n = 0; n < 8; n++) {
        float o = agg[(size_t)(n0 + n) * 64 + j];
        gs[n][j] = 0.5f * o * (1.f + erff(o * 0.70710678118654752f));
    }
    __syncthreads();
    const float* W = Wout + (size_t)(layer * 3 + t) * HID * HID;
    float b = bout[(layer * 3 + t) * HID + j];
    float acc[8];
    #pragma unroll
    for (int n = 0; n < 8; n++) acc[n] = b;
    for (int i = 0; i < 64; i++) {
        float w = W[i * 64 + j];
        #pragma unroll
        for (int n = 0; n < 8; n++) acc[n] += gs[n][i] * w;
    }
    float g = 1.f / (1.f + __expf(-skip[layer * 3 + t]));
    #pragma unroll
    for (int n = 0; n < 8; n++) {
        float r = g * acc[n] + (1.f - g) * h[(size_t)(n0 + n) * 64 + j];
        h[(size_t)(n0 + n) * 64 + j] = fmaxf(r, 0.f);
    }
}

// ---------------- final l2 normalize ----------------
__global__ void k_l2(const float* __restrict__ h, float* __restrict__ out) {
    int node = blockIdx.x, j = threadIdx.x;   // 64 = one wave
    float v = h[(size_t)node * HID + j];
    float ss = v * v;
    #pragma unroll
    for (int off = 32; off > 0; off >>= 1) ss += __shfl_down(ss, off);
    ss = __shfl(ss, 0);
    float nrm = fmaxf(sqrtf(ss), 1e-12f);
    out[(size_t)node * HID + j] = v / nrm;
}

extern "C" void kernel_launch(void* const* d_in, const int* in_sizes, int n_in,
                              void* d_out, int out_size, void* d_ws, size_t ws_size,
                              hipStream_t stream) {
    const float* xu   = (const float*)d_in[0];
    const float* xe   = (const float*)d_in[1];
    const float* xv   = (const float*)d_in[2];
    const float* Wu   = (const float*)d_in[3];
    const float* bu   = (const float*)d_in[4];
    const float* We   = (const float*)d_in[5];
    const float* be   = (const float*)d_in[6];
    const float* Wv_  = (const float*)d_in[7];
    const float* bv   = (const float*)d_in[8];
    const float* embu = (const float*)d_in[9];
    const float* embe = (const float*)d_in[10];
    const float* embv = (const float*)d_in[11];
    const float* Wkqv = (const float*)d_in[12];
    const float* bkqv = (const float*)d_in[13];
    const float* Wk   = (const float*)d_in[14];
    const float* Wv   = (const float*)d_in[15];
    const float* prel = (const float*)d_in[16];
    const float* Wout = (const float*)d_in[17];
    const float* bout = (const float*)d_in[18];
    const float* skip = (const float*)d_in[19];
    const int*   idu  = (const int*)d_in[20];
    const int*   ide  = (const int*)d_in[21];
    const int*   idv  = (const int*)d_in[22];
    EdgePtrs ep;
    for (int e = 0; e < 13; e++) ep.p[e] = (const int*)d_in[23 + e];

    float* ws  = (float*)d_ws;
    float* h    = ws;                                   // NTOT*64   = 5,824,000
    float* kqv  = h   + (size_t)NTOT * HID;             // NTOT*192  = 17,472,000
    float* sc   = kqv + (size_t)NTOT * 192;             // ETOT*4    = 3,480,000
    float* agg  = sc  + (size_t)ETOT * HEADS;           // NTOT*64   = 5,824,000
    int* cnt     = (int*)(agg + (size_t)NTOT * HID);    // NTOT
    int* cursor  = cnt + NTOT;                          // NTOT
    int* row_ptr = cursor + NTOT;                       // NTOT+1
    int* partial = row_ptr + NTOT + 1;                  // 513 (pad to even for int2 align)
    int2* csr    = (int2*)(partial + 513);              // ETOT int2

    k_init<<<(NTOT * HID + 255) / 256, 256, 0, stream>>>(
        xu, xe, xv, Wu, bu, We, be, Wv_, bv, embu, embe, embv, idu, ide, idv, h);

    // CSR build (edges are layer-invariant)
    hipMemsetAsync(cnt, 0, (size_t)2 * NTOT * 4, stream);   // cnt + cursor
    int nblk = (NTOT + 255) / 256;   // 356
    k_cnt<<<(ETOT + 255) / 256, 256, 0, stream>>>(ep, cnt);
    k_scan_a<<<nblk, 256, 0, stream>>>(cnt, partial);
    k_scan_b<<<1, 512, 0, stream>>>(partial, nblk);
    k_scan_c<<<nblk, 256, 0, stream>>>(cnt, partial, row_ptr);
    k_fill<<<(ETOT + 255) / 256, 256, 0, stream>>>(ep, row_ptr, cursor, csr);

    for (int l = 0; l < LAYERS; l++) {
        k_kqv<<<NTOT / 8, 192, 0, stream>>>(h, Wkqv, bkqv, kqv, l);
        k_score<<<(ETOT * HEADS + 255) / 256, 256, 0, stream>>>(kqv, Wk, prel, sc, ep, l);
        k_gather<<<(NTOT + 7) / 8, 512, 0, stream>>>(kqv, sc, Wv, row_ptr, csr, agg, l);
        k_out<<<NTOT / 8, 64, 0, stream>>>(agg, Wout, bout, skip, h, l);
    }
    k_l2<<<NTOT, HID, 0, stream>>>(h, (float*)d_out);
}

// Round 3
// 1487.442 us; speedup vs baseline: 5.2897x; 1.3821x over previous
//
#include <hip/hip_runtime.h>
#include <hip/hip_fp16.h>
#include <math.h>

#define HID   64
#define HEADS 4
#define DH    16
#define NU    30000
#define NE_   60000
#define NV    1000
#define NTOT  91000
#define ETOT  870000
#define LAYERS 2

// Edge-type tables
__device__ const int d_EOFF[14] = {0,150000,270000,330000,370000,400000,450000,
                                   570000,630000,670000,700000,750000,810000,870000};
__device__ const int d_ECNT[13] = {150000,120000,60000,40000,30000,50000,
                                   120000,60000,40000,30000,50000,60000,60000};
__device__ const int d_EST[13]  = {0,0,0,0,0,0,1,1,1,1,1,1,2};
__device__ const int d_EDT[13]  = {0,1,1,1,1,1,0,0,0,0,0,2,1};
// local (per-dst-type) edge-type index: user gets {e0,e6..e10}, event {e1..e5,e12}, venue {e11}
__device__ const int d_EL[13]   = {0, 0,1,2,3,4, 1,2,3,4,5, 0, 5};
// inverse: el -> e, per dst type
__device__ const int d_ELMAP[3][6] = {{0,6,7,8,9,10},{1,2,3,4,5,12},{11,11,11,11,11,11}};
__device__ const int d_NOFF[3]  = {0, NU, NU + NE_};

struct EdgePtrs { const int* p[13]; };

__device__ __forceinline__ int node_type(int n) {
    return (n >= NU) + (n >= NU + NE_);
}

// ---------------- input projection: h = x@W + b + emb[ids] ----------------
__global__ void k_init(const float* __restrict__ xu, const float* __restrict__ xe,
                       const float* __restrict__ xv,
                       const float* __restrict__ Wu, const float* __restrict__ bu,
                       const float* __restrict__ We, const float* __restrict__ be,
                       const float* __restrict__ Wv_, const float* __restrict__ bv,
                       const float* __restrict__ embu, const float* __restrict__ embe,
                       const float* __restrict__ embv,
                       const int* __restrict__ idu, const int* __restrict__ ide,
                       const int* __restrict__ idv,
                       float* __restrict__ h) {
    int gid = blockIdx.x * blockDim.x + threadIdx.x;
    if (gid >= NTOT * HID) return;
    int node = gid >> 6, j = gid & 63;
    const float *x, *W, *b, *emb; const int* ids; int in_dim, n;
    if (node < NU)            { n = node;           x = xu; W = Wu;  b = bu; emb = embu; ids = idu; in_dim = 32; }
    else if (node < NU + NE_) { n = node - NU;      x = xe; W = We;  b = be; emb = embe; ids = ide; in_dim = 32; }
    else                      { n = node - NU - NE_;x = xv; W = Wv_; b = bv; emb = embv; ids = idv; in_dim = 16; }
    float acc = b[j] + emb[(size_t)ids[n] * HID + j];
    for (int i = 0; i < in_dim; i++) acc += x[(size_t)n * in_dim + i] * W[i * HID + j];
    h[gid] = acc;
}

// ---------------- CSR build ----------------
__global__ void k_cnt(EdgePtrs ep, int* __restrict__ cnt) {
    int eidx = blockIdx.x * blockDim.x + threadIdx.x;
    if (eidx >= ETOT) return;
    int e = 0;
    #pragma unroll
    for (int i = 1; i < 13; i++) e += (eidx >= d_EOFF[i]);
    int li = eidx - d_EOFF[e];
    int dst = ep.p[e][d_ECNT[e] + li];
    atomicAdd(&cnt[d_NOFF[d_EDT[e]] + dst], 1);
}

__global__ void k_scan_a(const int* __restrict__ cnt, int* __restrict__ partial) {
    __shared__ int s[256];
    int i = blockIdx.x * 256 + threadIdx.x;
    s[threadIdx.x] = (i < NTOT) ? cnt[i] : 0;
    __syncthreads();
    for (int off = 128; off > 0; off >>= 1) {
        if (threadIdx.x < off) s[threadIdx.x] += s[threadIdx.x + off];
        __syncthreads();
    }
    if (threadIdx.x == 0) partial[blockIdx.x] = s[0];
}

__global__ void k_scan_b(int* __restrict__ partial, int nblk) {
    __shared__ int s[512];
    int t = threadIdx.x;
    s[t] = (t < nblk) ? partial[t] : 0;
    __syncthreads();
    for (int off = 1; off < 512; off <<= 1) {
        int v = (t >= off) ? s[t - off] : 0;
        __syncthreads();
        s[t] += v;
        __syncthreads();
    }
    if (t < nblk) partial[t] = t ? s[t - 1] : 0;   // exclusive
}

__global__ void k_scan_c(const int* __restrict__ cnt, const int* __restrict__ partial,
                         int* __restrict__ row_ptr) {
    __shared__ int s[256];
    int i = blockIdx.x * 256 + threadIdx.x, t = threadIdx.x;
    int v = (i < NTOT) ? cnt[i] : 0;
    s[t] = v;
    __syncthreads();
    for (int off = 1; off < 256; off <<= 1) {
        int u = (t >= off) ? s[t - off] : 0;
        __syncthreads();
        s[t] += u;
        __syncthreads();
    }
    if (i < NTOT) row_ptr[i] = s[t] - v + partial[blockIdx.x];
    if (i == NTOT - 1) row_ptr[NTOT] = ETOT;
}

__global__ void k_fill(EdgePtrs ep, const int* __restrict__ row_ptr,
                       int* __restrict__ cursor, int* __restrict__ csr) {
    int eidx = blockIdx.x * blockDim.x + threadIdx.x;
    if (eidx >= ETOT) return;
    int e = 0;
    #pragma unroll
    for (int i = 1; i < 13; i++) e += (eidx >= d_EOFF[i]);
    int li = eidx - d_EOFF[e];
    const int* base = ep.p[e];
    int src = base[li], dst = base[d_ECNT[e] + li];
    int sg = d_NOFF[d_EST[e]] + src;
    int dg = d_NOFF[d_EDT[e]] + dst;
    int pos = atomicAdd(&cursor[dg], 1);
    csr[row_ptr[dg] + pos] = sg | (e << 17) | (d_EL[e] << 21);
}

// ---------------- kqv: q -> fp32 kq buffer; k,v -> packed fp16 ----------------
__global__ void k_kqv(const float* __restrict__ h, const float* __restrict__ Wkqv,
                      const float* __restrict__ bkqv, float* __restrict__ q_out,
                      __half2* __restrict__ kv, int layer) {
    int n0 = blockIdx.x * 8;
    int t = node_type(n0);          // 8-node tiles never straddle type boundaries
    __shared__ float hs[8][64];
    __shared__ float ls[8][192];
    for (int i = threadIdx.x; i < 512; i += 192)
        hs[i >> 6][i & 63] = h[(size_t)n0 * 64 + i];
    __syncthreads();
    const float* W = Wkqv + (size_t)(layer * 3 + t) * HID * 192;
    int j = threadIdx.x;
    float b = bkqv[(layer * 3 + t) * 192 + j];
    float acc[8];
    #pragma unroll
    for (int n = 0; n < 8; n++) acc[n] = b;
    for (int i = 0; i < 64; i++) {
        float w = W[i * 192 + j];
        #pragma unroll
        for (int n = 0; n < 8; n++) acc[n] += hs[n][i] * w;
    }
    #pragma unroll
    for (int n = 0; n < 8; n++) ls[n][j] = acc[n];
    __syncthreads();
    if (j < 64) {
        #pragma unroll
        for (int n = 0; n < 8; n++)
            kv[(size_t)(n0 + n) * 64 + j] = __floats2half2_rn(ls[n][j], ls[n][128 + j]);
    } else if (j < 128) {
        #pragma unroll
        for (int n = 0; n < 8; n++)
            q_out[(size_t)(n0 + n) * 64 + (j - 64)] = ls[n][j];
    }
}

// ---------------- fused gather: score + online softmax + message agg ----------------
#define WVSTRIDE 264   // 256 + 8: head groups 8 banks apart -> 2-way aliasing (free)
__global__ __launch_bounds__(512)
void k_gather(const float* __restrict__ q_in, const __half2* __restrict__ kv,
              const float* __restrict__ Wk, const float* __restrict__ Wv,
              const float* __restrict__ prel, const int* __restrict__ row_ptr,
              const int* __restrict__ csr, float* __restrict__ agg, int layer) {
    __shared__ float wv[13 * 4 * WVSTRIDE];
    __shared__ float sprel[52];
    for (int i = threadIdx.x; i < 13 * 4 * 256; i += 512) {
        int g = i >> 8, r = i & 255;
        wv[g * WVSTRIDE + r] = Wv[(size_t)layer * 13312 + i];
    }
    if (threadIdx.x < 52) sprel[threadIdx.x] = prel[layer * 52 + threadIdx.x] * 0.25f;
    __syncthreads();
    int wave = threadIdx.x >> 6, lane = threadIdx.x & 63;
    int node = blockIdx.x * 8 + wave;
    if (node >= NTOT) return;
    int hh = lane & 48;          // h*16
    int x  = lane & 15;
    int t = node_type(node);
    float q = q_in[(size_t)node * 64 + lane];   // q[h][x]
    // precompute qw[el][d]: lane (h, d=x) holds sum_x Wk[e,h,d,x]*q[h,x]
    float qw0 = 0.f, qw1 = 0.f, qw2 = 0.f, qw3 = 0.f, qw4 = 0.f, qw5 = 0.f;
    {
        int nel = (t == 2) ? 1 : 6;
        for (int el = 0; el < nel; el++) {
            int e = d_ELMAP[t][el];
            const float* Wkp = Wk + (((size_t)layer * 13 + e) * 4 + (lane >> 4)) * 256 + x * 16;
            float a = 0.f;
            #pragma unroll
            for (int xx = 0; xx < 16; xx++) a += Wkp[xx] * __shfl(q, hh + xx, 64);
            if (el == 0) qw0 = a; else if (el == 1) qw1 = a; else if (el == 2) qw2 = a;
            else if (el == 3) qw3 = a; else if (el == 4) qw4 = a; else qw5 = a;
        }
    }
    int beg = row_ptr[node], end = row_ptr[node + 1];
    float m = -1e30f, l = 0.f, acc = 0.f;
    const float* wvx = &wv[x];
    for (int i = beg; i < end; i++) {
        int c = csr[i];
        int sg = c & 0x1FFFF, e = (c >> 17) & 15, el = (c >> 21) & 7;
        __half2 kv2 = kv[(size_t)sg * 64 + lane];   // coalesced 256B gather
        float kf = __low2float(kv2), vf = __high2float(kv2);
        float qsel = (el == 0) ? qw0 : (el == 1) ? qw1 : (el == 2) ? qw2
                   : (el == 3) ? qw3 : (el == 4) ? qw4 : qw5;
        float s = kf * qsel;
        #pragma unroll
        for (int off = 1; off < 16; off <<= 1) s += __shfl_xor(s, off, 64);
        int eh4 = e * 4 + (lane >> 4);
        s *= sprel[eh4];
        const float* wbase = wvx + eh4 * WVSTRIDE;
        float ve = 0.f;
        #pragma unroll
        for (int d = 0; d < 16; d++)
            ve += __shfl(vf, hh + d, 64) * wbase[d * 16];
        float m2  = fmaxf(m, s);
        float sc1 = __expf(m - m2);
        float es  = __expf(s - m2);
        l   = l * sc1 + es;
        acc = acc * sc1 + es * ve;
        m = m2;
    }
    agg[(size_t)node * 64 + lane] = (l > 0.f) ? acc / l : 0.f;
}

// ---------------- epilogue: gelu -> @Wout + bout -> skip-gate -> relu ----------------
__global__ void k_out(const float* __restrict__ agg, const float* __restrict__ Wout,
                      const float* __restrict__ bout, const float* __restrict__ skip,
                      float* __restrict__ h, int layer) {
    int n0 = blockIdx.x * 8;
    int t = node_type(n0);
    int j = threadIdx.x;                 // 64 threads
    __shared__ float gs[8][64];
    #pragma unroll
    for (int n = 0; n < 8; n++) {
        float o = agg[(size_t)(n0 + n) * 64 + j];
        gs[n][j] = 0.5f * o * (1.f + erff(o * 0.70710678118654752f));
    }
    __syncthreads();
    const float* W = Wout + (size_t)(layer * 3 + t) * HID * HID;
    float b = bout[(layer * 3 + t) * HID + j];
    float acc[8];
    #pragma unroll
    for (int n = 0; n < 8; n++) acc[n] = b;
    for (int i = 0; i < 64; i++) {
        float w = W[i * 64 + j];
        #pragma unroll
        for (int n = 0; n < 8; n++) acc[n] += gs[n][i] * w;
    }
    float g = 1.f / (1.f + __expf(-skip[layer * 3 + t]));
    #pragma unroll
    for (int n = 0; n < 8; n++) {
        float r = g * acc[n] + (1.f - g) * h[(size_t)(n0 + n) * 64 + j];
        h[(size_t)(n0 + n) * 64 + j] = fmaxf(r, 0.f);
    }
}

// ---------------- final l2 normalize ----------------
__global__ void k_l2(const float* __restrict__ h, float* __restrict__ out) {
    int node = blockIdx.x, j = threadIdx.x;   // 64 = one wave
    float v = h[(size_t)node * HID + j];
    float ss = v * v;
    #pragma unroll
    for (int off = 32; off > 0; off >>= 1) ss += __shfl_down(ss, off);
    ss = __shfl(ss, 0);
    float nrm = fmaxf(sqrtf(ss), 1e-12f);
    out[(size_t)node * HID + j] = v / nrm;
}

extern "C" void kernel_launch(void* const* d_in, const int* in_sizes, int n_in,
                              void* d_out, int out_size, void* d_ws, size_t ws_size,
                              hipStream_t stream) {
    const float* xu   = (const float*)d_in[0];
    const float* xe   = (const float*)d_in[1];
    const float* xv   = (const float*)d_in[2];
    const float* Wu   = (const float*)d_in[3];
    const float* bu   = (const float*)d_in[4];
    const float* We   = (const float*)d_in[5];
    const float* be   = (const float*)d_in[6];
    const float* Wv_  = (const float*)d_in[7];
    const float* bv   = (const float*)d_in[8];
    const float* embu = (const float*)d_in[9];
    const float* embe = (const float*)d_in[10];
    const float* embv = (const float*)d_in[11];
    const float* Wkqv = (const float*)d_in[12];
    const float* bkqv = (const float*)d_in[13];
    const float* Wk   = (const float*)d_in[14];
    const float* Wv   = (const float*)d_in[15];
    const float* prel = (const float*)d_in[16];
    const float* Wout = (const float*)d_in[17];
    const float* bout = (const float*)d_in[18];
    const float* skip = (const float*)d_in[19];
    const int*   idu  = (const int*)d_in[20];
    const int*   ide  = (const int*)d_in[21];
    const int*   idv  = (const int*)d_in[22];
    EdgePtrs ep;
    for (int e = 0; e < 13; e++) ep.p[e] = (const int*)d_in[23 + e];

    float* ws  = (float*)d_ws;
    float* h     = ws;                                  // NTOT*64 f32
    float* q_buf = h     + (size_t)NTOT * HID;          // NTOT*64 f32
    float* agg   = q_buf + (size_t)NTOT * HID;          // NTOT*64 f32
    __half2* kv  = (__half2*)(agg + (size_t)NTOT * HID);// NTOT*64 half2
    int* cnt     = (int*)(kv + (size_t)NTOT * HID);     // NTOT
    int* cursor  = cnt + NTOT;                          // NTOT
    int* row_ptr = cursor + NTOT;                       // NTOT+1
    int* partial = row_ptr + NTOT + 1;                  // 512
    int* csr     = partial + 512;                       // ETOT int

    k_init<<<(NTOT * HID + 255) / 256, 256, 0, stream>>>(
        xu, xe, xv, Wu, bu, We, be, Wv_, bv, embu, embe, embv, idu, ide, idv, h);

    // CSR build (edges are layer-invariant)
    hipMemsetAsync(cnt, 0, (size_t)2 * NTOT * 4, stream);   // cnt + cursor
    int nblk = (NTOT + 255) / 256;   // 356
    k_cnt<<<(ETOT + 255) / 256, 256, 0, stream>>>(ep, cnt);
    k_scan_a<<<nblk, 256, 0, stream>>>(cnt, partial);
    k_scan_b<<<1, 512, 0, stream>>>(partial, nblk);
    k_scan_c<<<nblk, 256, 0, stream>>>(cnt, partial, row_ptr);
    k_fill<<<(ETOT + 255) / 256, 256, 0, stream>>>(ep, row_ptr, cursor, csr);

    for (int l = 0; l < LAYERS; l++) {
        k_kqv<<<NTOT / 8, 192, 0, stream>>>(h, Wkqv, bkqv, q_buf, kv, l);
        k_gather<<<(NTOT + 7) / 8, 512, 0, stream>>>(q_buf, kv, Wk, Wv, prel,
                                                     row_ptr, csr, agg, l);
        k_out<<<NTOT / 8, 64, 0, stream>>>(agg, Wout, bout, skip, h, l);
    }
    k_l2<<<NTOT, HID, 0, stream>>>(h, (float*)d_out);
}

// Round 4
// 1242.705 us; speedup vs baseline: 6.3315x; 1.1969x over previous
//
#include <hip/hip_runtime.h>
#include <hip/hip_fp16.h>
#include <math.h>

#define HID   64
#define HEADS 4
#define DH    16
#define NU    30000
#define NE_   60000
#define NV    1000
#define NTOT  91000
#define ETOT  870000
#define NSLOT 541000
#define LAYERS 2

// Edge-type tables
__device__ const int d_EOFF[14] = {0,150000,270000,330000,370000,400000,450000,
                                   570000,630000,670000,700000,750000,810000,870000};
__device__ const int d_ECNT[13] = {150000,120000,60000,40000,30000,50000,
                                   120000,60000,40000,30000,50000,60000,60000};
__device__ const int d_EST[13]  = {0,0,0,0,0,0,1,1,1,1,1,1,2};
__device__ const int d_EDT[13]  = {0,1,1,1,1,1,0,0,0,0,0,2,1};
// local (per-dst-type) edge-type index
__device__ const int d_EL[13]   = {0, 0,1,2,3,4, 1,2,3,4,5, 0, 5};
// inverse: el -> e, per dst type
__device__ const int d_ELMAP[3][6] = {{0,6,7,8,9,10},{1,2,3,4,5,12},{11,11,11,11,11,11}};
__device__ const int d_NOFF[3]  = {0, NU, NU + NE_};
// slot base per edge type in the vt mega-table (src-node indexed per e)
__device__ const int d_EBASE[13] = {0,30000,60000,90000,120000,150000,
                                    180000,240000,300000,360000,420000,480000,540000};

struct EdgePtrs { const int* p[13]; };

__device__ __forceinline__ int node_type(int n) {
    return (n >= NU) + (n >= NU + NE_);
}

// ---------------- input projection: h = x@W + b + emb[ids] ----------------
__global__ void k_init(const float* __restrict__ xu, const float* __restrict__ xe,
                       const float* __restrict__ xv,
                       const float* __restrict__ Wu, const float* __restrict__ bu,
                       const float* __restrict__ We, const float* __restrict__ be,
                       const float* __restrict__ Wv_, const float* __restrict__ bv,
                       const float* __restrict__ embu, const float* __restrict__ embe,
                       const float* __restrict__ embv,
                       const int* __restrict__ idu, const int* __restrict__ ide,
                       const int* __restrict__ idv,
                       float* __restrict__ h) {
    int gid = blockIdx.x * blockDim.x + threadIdx.x;
    if (gid >= NTOT * HID) return;
    int node = gid >> 6, j = gid & 63;
    const float *x, *W, *b, *emb; const int* ids; int in_dim, n;
    if (node < NU)            { n = node;           x = xu; W = Wu;  b = bu; emb = embu; ids = idu; in_dim = 32; }
    else if (node < NU + NE_) { n = node - NU;      x = xe; W = We;  b = be; emb = embe; ids = ide; in_dim = 32; }
    else                      { n = node - NU - NE_;x = xv; W = Wv_; b = bv; emb = embv; ids = idv; in_dim = 16; }
    float acc = b[j] + emb[(size_t)ids[n] * HID + j];
    for (int i = 0; i < in_dim; i++) acc += x[(size_t)n * in_dim + i] * W[i * HID + j];
    h[gid] = acc;
}

// ---------------- CSR build (rows padded to even length) ----------------
__global__ void k_cnt(EdgePtrs ep, int* __restrict__ cnt) {
    int eidx = blockIdx.x * blockDim.x + threadIdx.x;
    if (eidx >= ETOT) return;
    int e = 0;
    #pragma unroll
    for (int i = 1; i < 13; i++) e += (eidx >= d_EOFF[i]);
    int li = eidx - d_EOFF[e];
    int dst = ep.p[e][d_ECNT[e] + li];
    atomicAdd(&cnt[d_NOFF[d_EDT[e]] + dst], 1);
}

__global__ void k_scan_a(const int* __restrict__ cnt, int* __restrict__ partial) {
    __shared__ int s[256];
    int i = blockIdx.x * 256 + threadIdx.x;
    int c = (i < NTOT) ? cnt[i] : 0;
    s[threadIdx.x] = c + (c & 1);          // padded to even
    __syncthreads();
    for (int off = 128; off > 0; off >>= 1) {
        if (threadIdx.x < off) s[threadIdx.x] += s[threadIdx.x + off];
        __syncthreads();
    }
    if (threadIdx.x == 0) partial[blockIdx.x] = s[0];
}

__global__ void k_scan_b(int* __restrict__ partial, int nblk) {
    __shared__ int s[512];
    int t = threadIdx.x;
    s[t] = (t < nblk) ? partial[t] : 0;
    __syncthreads();
    for (int off = 1; off < 512; off <<= 1) {
        int v = (t >= off) ? s[t - off] : 0;
        __syncthreads();
        s[t] += v;
        __syncthreads();
    }
    if (t < nblk) partial[t] = t ? s[t - 1] : 0;   // exclusive
}

__global__ void k_scan_c(const int* __restrict__ cnt, const int* __restrict__ partial,
                         int* __restrict__ row_ptr) {
    __shared__ int s[256];
    int i = blockIdx.x * 256 + threadIdx.x, t = threadIdx.x;
    int c = (i < NTOT) ? cnt[i] : 0;
    int v = c + (c & 1);                   // padded
    s[t] = v;
    __syncthreads();
    for (int off = 1; off < 256; off <<= 1) {
        int u = (t >= off) ? s[t - off] : 0;
        __syncthreads();
        s[t] += u;
        __syncthreads();
    }
    if (i < NTOT) row_ptr[i] = s[t] - v + partial[blockIdx.x];
    if (i == NTOT - 1) row_ptr[NTOT] = s[t] + partial[blockIdx.x];
}

__global__ void k_fill(EdgePtrs ep, const int* __restrict__ row_ptr,
                       int* __restrict__ cursor, int2* __restrict__ csr) {
    int eidx = blockIdx.x * blockDim.x + threadIdx.x;
    if (eidx >= ETOT) return;
    int e = 0;
    #pragma unroll
    for (int i = 1; i < 13; i++) e += (eidx >= d_EOFF[i]);
    int li = eidx - d_EOFF[e];
    const int* base = ep.p[e];
    int src = base[li], dst = base[d_ECNT[e] + li];
    int sg = d_NOFF[d_EST[e]] + src;
    int dg = d_NOFF[d_EDT[e]] + dst;
    int pos = atomicAdd(&cursor[dg], 1);
    csr[row_ptr[dg] + pos] = make_int2(sg | (d_EL[e] << 17), d_EBASE[e] + src);
}

// ---------------- kqv: q -> fp32; k,v -> separate half tables ----------------
__global__ void k_kqv(const float* __restrict__ h, const float* __restrict__ Wkqv,
                      const float* __restrict__ bkqv, float* __restrict__ qagg,
                      __half* __restrict__ ktab, __half* __restrict__ vtab, int layer) {
    int n0 = blockIdx.x * 8;
    int t = node_type(n0);          // 8-node tiles never straddle type boundaries
    __shared__ float hs[8][64];
    for (int i = threadIdx.x; i < 512; i += 192)
        hs[i >> 6][i & 63] = h[(size_t)n0 * 64 + i];
    __syncthreads();
    const float* W = Wkqv + (size_t)(layer * 3 + t) * HID * 192;
    int j = threadIdx.x;
    float b = bkqv[(layer * 3 + t) * 192 + j];
    float acc[8];
    #pragma unroll
    for (int n = 0; n < 8; n++) acc[n] = b;
    for (int i = 0; i < 64; i++) {
        float w = W[i * 192 + j];
        #pragma unroll
        for (int n = 0; n < 8; n++) acc[n] += hs[n][i] * w;
    }
    if (j < 64) {
        #pragma unroll
        for (int n = 0; n < 8; n++) ktab[(size_t)(n0 + n) * 64 + j] = __float2half(acc[n]);
    } else if (j < 128) {
        #pragma unroll
        for (int n = 0; n < 8; n++) qagg[(size_t)(n0 + n) * 64 + (j - 64)] = acc[n];
    } else {
        #pragma unroll
        for (int n = 0; n < 8; n++) vtab[(size_t)(n0 + n) * 64 + (j - 128)] = __float2half(acc[n]);
    }
}

// ---------------- vt precompute: vttab[slot] = v[src] @ Wv[e]  ----------------
#define WVS 264   // 4 heads * 264 floats, 8-bank offset per head -> <=2-way (free)
__global__ __launch_bounds__(512)
void k_trans(const __half* __restrict__ vtab, const float* __restrict__ Wv,
             __half* __restrict__ vttab, int layer) {
    int s0 = blockIdx.x * 8;
    int e = 0;
    #pragma unroll
    for (int i = 1; i < 13; i++) e += (s0 >= d_EBASE[i]);   // whole block same e
    __shared__ float swv[4 * WVS];
    for (int i = threadIdx.x; i < 1024; i += 512)
        swv[(i >> 8) * WVS + (i & 255)] = Wv[((size_t)layer * 13 + e) * 1024 + i];
    __syncthreads();
    int wave = threadIdx.x >> 6, lane = threadIdx.x & 63;
    int slot = s0 + wave;
    int hh = lane & 48, x = lane & 15;
    int node = d_NOFF[d_EST[e]] + slot - d_EBASE[e];
    float vf = __half2float(vtab[(size_t)node * 64 + lane]);
    const float* wb = &swv[(lane >> 4) * WVS + x];
    float vt = 0.f;
    #pragma unroll
    for (int d = 0; d < 16; d++)
        vt += __shfl(vf, hh + d, 64) * wb[d * 16];
    vttab[(size_t)slot * 64 + lane] = __float2half(vt);
}

// ---------------- fused gather: score + online softmax + message agg ----------------
__global__ __launch_bounds__(512)
void k_gather(float* __restrict__ qagg, const __half* __restrict__ ktab,
              const __half* __restrict__ vttab, const float* __restrict__ Wk,
              const float* __restrict__ prel, const int* __restrict__ row_ptr,
              const int2* __restrict__ csr, int layer) {
    int wave = threadIdx.x >> 6, lane = threadIdx.x & 63;
    int node = blockIdx.x * 8 + wave;
    if (node >= NTOT) return;
    int hh = lane & 48, x = lane & 15, hq = lane >> 4;
    int t = node_type(node);
    float q = qagg[(size_t)node * 64 + lane];   // q[h][x]
    // qw[el][d] = p_rel*scale * sum_x Wk[e,h,d,x] * q[h,x]; lane's x plays d
    float qw0 = 0.f, qw1 = 0.f, qw2 = 0.f, qw3 = 0.f, qw4 = 0.f, qw5 = 0.f;
    int nel = (t == 2) ? 1 : 6;
    for (int el = 0; el < nel; el++) {
        int e = d_ELMAP[t][el];
        const float* Wkp = Wk + (((size_t)layer * 13 + e) * 4 + hq) * 256 + x * 16;
        float a = 0.f;
        #pragma unroll
        for (int xx = 0; xx < 16; xx++) a += Wkp[xx] * __shfl(q, hh + xx, 64);
        a *= prel[(layer * 13 + e) * 4 + hq] * 0.25f;
        if (el == 0) qw0 = a; else if (el == 1) qw1 = a; else if (el == 2) qw2 = a;
        else if (el == 3) qw3 = a; else if (el == 4) qw4 = a; else qw5 = a;
    }
    int beg = row_ptr[node], end = row_ptr[node + 1];
    float m = -1e30f, l = 0.f, acc = 0.f;

    int2 cA, cB; __half kA, kB, vA, vB;
    int i = beg;
    if (i < end) {
        cA = csr[i]; cB = csr[i + 1];
        int ndA = (cA.x >= 0) ? (cA.x & 0x1FFFF) : 0, slA = (cA.x >= 0) ? cA.y : 0;
        int ndB = (cB.x >= 0) ? (cB.x & 0x1FFFF) : 0, slB = (cB.x >= 0) ? cB.y : 0;
        kA = ktab[(size_t)ndA * 64 + lane];  vA = vttab[(size_t)slA * 64 + lane];
        kB = ktab[(size_t)ndB * 64 + lane];  vB = vttab[(size_t)slB * 64 + lane];
    }
    while (i < end) {
        int2 pA = cA, pB = cB;
        __half ka = kA, va = vA, kb = kB, vb = vB;
        i += 2;
        if (i < end) {   // prefetch next pair
            cA = csr[i]; cB = csr[i + 1];
            int ndA = (cA.x >= 0) ? (cA.x & 0x1FFFF) : 0, slA = (cA.x >= 0) ? cA.y : 0;
            int ndB = (cB.x >= 0) ? (cB.x & 0x1FFFF) : 0, slB = (cB.x >= 0) ? cB.y : 0;
            kA = ktab[(size_t)ndA * 64 + lane];  vA = vttab[(size_t)slA * 64 + lane];
            kB = ktab[(size_t)ndB * 64 + lane];  vB = vttab[(size_t)slB * 64 + lane];
        }
        // ---- edge A ----
        {
            int el = (pA.x >> 17) & 7;
            float qsel = (el == 0) ? qw0 : (el == 1) ? qw1 : (el == 2) ? qw2
                       : (el == 3) ? qw3 : (el == 4) ? qw4 : qw5;
            float s = __half2float(ka) * qsel;
            s += __shfl_xor(s, 1, 64); s += __shfl_xor(s, 2, 64);
            s += __shfl_xor(s, 4, 64); s += __shfl_xor(s, 8, 64);
            bool valid = pA.x >= 0;
            s = valid ? s : -1e30f;
            float m2  = fmaxf(m, s);
            float sc1 = __expf(m - m2);
            float es  = valid ? __expf(s - m2) : 0.f;
            l   = l * sc1 + es;
            acc = acc * sc1 + es * __half2float(va);
            m = m2;
        }
        // ---- edge B ----
        {
            int el = (pB.x >> 17) & 7;
            float qsel = (el == 0) ? qw0 : (el == 1) ? qw1 : (el == 2) ? qw2
                       : (el == 3) ? qw3 : (el == 4) ? qw4 : qw5;
            float s = __half2float(kb) * qsel;
            s += __shfl_xor(s, 1, 64); s += __shfl_xor(s, 2, 64);
            s += __shfl_xor(s, 4, 64); s += __shfl_xor(s, 8, 64);
            bool valid = pB.x >= 0;
            s = valid ? s : -1e30f;
            float m2  = fmaxf(m, s);
            float sc1 = __expf(m - m2);
            float es  = valid ? __expf(s - m2) : 0.f;
            l   = l * sc1 + es;
            acc = acc * sc1 + es * __half2float(vb);
            m = m2;
        }
    }
    qagg[(size_t)node * 64 + lane] = (l > 0.f) ? acc / l : 0.f;
}

// ---------------- epilogue: gelu -> @Wout + bout -> skip-gate -> relu ----------------
__global__ void k_out(const float* __restrict__ agg, const float* __restrict__ Wout,
                      const float* __restrict__ bout, const float* __restrict__ skip,
                      float* __restrict__ h, int layer) {
    int n0 = blockIdx.x * 8;
    int t = node_type(n0);
    int j = threadIdx.x;                 // 64 threads
    __shared__ float gs[8][64];
    #pragma unroll
    for (int n = 0; n < 8; n++) {
        float o = agg[(size_t)(n0 + n) * 64 + j];
        gs[n][j] = 0.5f * o * (1.f + erff(o * 0.70710678118654752f));
    }
    __syncthreads();
    const float* W = Wout + (size_t)(layer * 3 + t) * HID * HID;
    float b = bout[(layer * 3 + t) * HID + j];
    float acc[8];
    #pragma unroll
    for (int n = 0; n < 8; n++) acc[n] = b;
    for (int i = 0; i < 64; i++) {
        float w = W[i * 64 + j];
        #pragma unroll
        for (int n = 0; n < 8; n++) acc[n] += gs[n][i] * w;
    }
    float g = 1.f / (1.f + __expf(-skip[layer * 3 + t]));
    #pragma unroll
    for (int n = 0; n < 8; n++) {
        float r = g * acc[n] + (1.f - g) * h[(size_t)(n0 + n) * 64 + j];
        h[(size_t)(n0 + n) * 64 + j] = fmaxf(r, 0.f);
    }
}

// ---------------- final l2 normalize ----------------
__global__ void k_l2(const float* __restrict__ h, float* __restrict__ out) {
    int node = blockIdx.x, j = threadIdx.x;   // 64 = one wave
    float v = h[(size_t)node * HID + j];
    float ss = v * v;
    #pragma unroll
    for (int off = 32; off > 0; off >>= 1) ss += __shfl_down(ss, off);
    ss = __shfl(ss, 0);
    float nrm = fmaxf(sqrtf(ss), 1e-12f);
    out[(size_t)node * HID + j] = v / nrm;
}

extern "C" void kernel_launch(void* const* d_in, const int* in_sizes, int n_in,
                              void* d_out, int out_size, void* d_ws, size_t ws_size,
                              hipStream_t stream) {
    const float* xu   = (const float*)d_in[0];
    const float* xe   = (const float*)d_in[1];
    const float* xv   = (const float*)d_in[2];
    const float* Wu   = (const float*)d_in[3];
    const float* bu   = (const float*)d_in[4];
    const float* We   = (const float*)d_in[5];
    const float* be   = (const float*)d_in[6];
    const float* Wv_  = (const float*)d_in[7];
    const float* bv   = (const float*)d_in[8];
    const float* embu = (const float*)d_in[9];
    const float* embe = (const float*)d_in[10];
    const float* embv = (const float*)d_in[11];
    const float* Wkqv = (const float*)d_in[12];
    const float* bkqv = (const float*)d_in[13];
    const float* Wk   = (const float*)d_in[14];
    const float* Wv   = (const float*)d_in[15];
    const float* prel = (const float*)d_in[16];
    const float* Wout = (const float*)d_in[17];
    const float* bout = (const float*)d_in[18];
    const float* skip = (const float*)d_in[19];
    const int*   idu  = (const int*)d_in[20];
    const int*   ide  = (const int*)d_in[21];
    const int*   idv  = (const int*)d_in[22];
    EdgePtrs ep;
    for (int e = 0; e < 13; e++) ep.p[e] = (const int*)d_in[23 + e];

    float* ws  = (float*)d_ws;
    float* h      = ws;                                    // NTOT*64 f32
    float* qagg   = h    + (size_t)NTOT * HID;             // NTOT*64 f32 (q, then agg)
    __half* ktab  = (__half*)(qagg + (size_t)NTOT * HID);  // NTOT*64 half
    __half* vtab  = ktab + (size_t)NTOT * HID;             // NTOT*64 half
    __half* vttab = vtab + (size_t)NTOT * HID;             // NSLOT*64 half
    int* cnt     = (int*)(vttab + (size_t)NSLOT * HID);    // NTOT
    int* cursor  = cnt + NTOT;                             // NTOT
    int* row_ptr = cursor + NTOT;                          // NTOT+1
    int* partial = row_ptr + NTOT + 1;                     // 512 (+pad for int2 align)
    int2* csr    = (int2*)(partial + 512 + 1);             // (ETOT+NTOT) int2

    k_init<<<(NTOT * HID + 255) / 256, 256, 0, stream>>>(
        xu, xe, xv, Wu, bu, We, be, Wv_, bv, embu, embe, embv, idu, ide, idv, h);

    // CSR build (edges are layer-invariant); rows padded to even, dummies = -1
    hipMemsetAsync(cnt, 0, (size_t)2 * NTOT * 4, stream);          // cnt + cursor
    hipMemsetAsync(csr, 0xFF, (size_t)(ETOT + NTOT) * 8, stream);  // dummy entries
    int nblk = (NTOT + 255) / 256;   // 356
    k_cnt<<<(ETOT + 255) / 256, 256, 0, stream>>>(ep, cnt);
    k_scan_a<<<nblk, 256, 0, stream>>>(cnt, partial);
    k_scan_b<<<1, 512, 0, stream>>>(partial, nblk);
    k_scan_c<<<nblk, 256, 0, stream>>>(cnt, partial, row_ptr);
    k_fill<<<(ETOT + 255) / 256, 256, 0, stream>>>(ep, row_ptr, cursor, csr);

    for (int l = 0; l < LAYERS; l++) {
        k_kqv<<<NTOT / 8, 192, 0, stream>>>(h, Wkqv, bkqv, qagg, ktab, vtab, l);
        k_trans<<<NSLOT / 8, 512, 0, stream>>>(vtab, Wv, vttab, l);
        k_gather<<<(NTOT + 7) / 8, 512, 0, stream>>>(qagg, ktab, vttab, Wk, prel,
                                                     row_ptr, csr, l);
        k_out<<<NTOT / 8, 64, 0, stream>>>(qagg, Wout, bout, skip, h, l);
    }
    k_l2<<<NTOT, HID, 0, stream>>>(h, (float*)d_out);
}

// Round 5
// 977.455 us; speedup vs baseline: 8.0496x; 1.2714x over previous
//
#include <hip/hip_runtime.h>
#include <hip/hip_fp16.h>
#include <math.h>

#define HID   64
#define HEADS 4
#define DH    16
#define NU    30000
#define NE_   60000
#define NV    1000
#define NTOT  91000
#define ETOT  870000
#define NSLOT 541000
#define LAYERS 2

// Edge-type tables
__device__ const int d_EOFF[14] = {0,150000,270000,330000,370000,400000,450000,
                                   570000,630000,670000,700000,750000,810000,870000};
__device__ const int d_ECNT[13] = {150000,120000,60000,40000,30000,50000,
                                   120000,60000,40000,30000,50000,60000,60000};
__device__ const int d_EST[13]  = {0,0,0,0,0,0,1,1,1,1,1,1,2};
__device__ const int d_EDT[13]  = {0,1,1,1,1,1,0,0,0,0,0,2,1};
// local (per-dst-type) edge-type index
__device__ const int d_EL[13]   = {0, 0,1,2,3,4, 1,2,3,4,5, 0, 5};
// inverse: el -> e, per dst type
__device__ const int d_ELMAP[3][6] = {{0,6,7,8,9,10},{1,2,3,4,5,12},{11,11,11,11,11,11}};
__device__ const int d_NOFF[3]  = {0, NU, NU + NE_};
// slot base per edge type in the vt mega-table (src-node indexed per e)
__device__ const int d_EBASE[13] = {0,30000,60000,90000,120000,150000,
                                    180000,240000,300000,360000,420000,480000,540000};
__device__ const int d_ESLOTS[13] = {30000,30000,30000,30000,30000,30000,
                                     60000,60000,60000,60000,60000,60000,1000};
// k_trans 64-slot block offsets per e: 6x469, 6x938, 1x16
__device__ const int d_TBOFF[14] = {0,469,938,1407,1876,2345,2814,
                                    3752,4690,5628,6566,7504,8442,8458};

struct EdgePtrs { const int* p[13]; };

__device__ __forceinline__ int node_type(int n) {
    return (n >= NU) + (n >= NU + NE_);
}

// ---------------- input projection: h = x@W + b + emb[ids] ----------------
__global__ void k_init(const float* __restrict__ xu, const float* __restrict__ xe,
                       const float* __restrict__ xv,
                       const float* __restrict__ Wu, const float* __restrict__ bu,
                       const float* __restrict__ We, const float* __restrict__ be,
                       const float* __restrict__ Wv_, const float* __restrict__ bv,
                       const float* __restrict__ embu, const float* __restrict__ embe,
                       const float* __restrict__ embv,
                       const int* __restrict__ idu, const int* __restrict__ ide,
                       const int* __restrict__ idv,
                       float* __restrict__ h) {
    int gid = blockIdx.x * blockDim.x + threadIdx.x;
    if (gid >= NTOT * HID) return;
    int node = gid >> 6, j = gid & 63;
    const float *x, *W, *b, *emb; const int* ids; int in_dim, n;
    if (node < NU)            { n = node;           x = xu; W = Wu;  b = bu; emb = embu; ids = idu; in_dim = 32; }
    else if (node < NU + NE_) { n = node - NU;      x = xe; W = We;  b = be; emb = embe; ids = ide; in_dim = 32; }
    else                      { n = node - NU - NE_;x = xv; W = Wv_; b = bv; emb = embv; ids = idv; in_dim = 16; }
    float acc = b[j] + emb[(size_t)ids[n] * HID + j];
    for (int i = 0; i < in_dim; i++) acc += x[(size_t)n * in_dim + i] * W[i * HID + j];
    h[gid] = acc;
}

// ---------------- CSR build (rows padded to even length) ----------------
__global__ void k_cnt(EdgePtrs ep, int* __restrict__ cnt) {
    int eidx = blockIdx.x * blockDim.x + threadIdx.x;
    if (eidx >= ETOT) return;
    int e = 0;
    #pragma unroll
    for (int i = 1; i < 13; i++) e += (eidx >= d_EOFF[i]);
    int li = eidx - d_EOFF[e];
    int dst = ep.p[e][d_ECNT[e] + li];
    atomicAdd(&cnt[d_NOFF[d_EDT[e]] + dst], 1);
}

__global__ void k_scan_a(const int* __restrict__ cnt, int* __restrict__ partial) {
    __shared__ int s[256];
    int i = blockIdx.x * 256 + threadIdx.x;
    int c = (i < NTOT) ? cnt[i] : 0;
    s[threadIdx.x] = c + (c & 1);          // padded to even
    __syncthreads();
    for (int off = 128; off > 0; off >>= 1) {
        if (threadIdx.x < off) s[threadIdx.x] += s[threadIdx.x + off];
        __syncthreads();
    }
    if (threadIdx.x == 0) partial[blockIdx.x] = s[0];
}

__global__ void k_scan_b(int* __restrict__ partial, int nblk) {
    __shared__ int s[512];
    int t = threadIdx.x;
    s[t] = (t < nblk) ? partial[t] : 0;
    __syncthreads();
    for (int off = 1; off < 512; off <<= 1) {
        int v = (t >= off) ? s[t - off] : 0;
        __syncthreads();
        s[t] += v;
        __syncthreads();
    }
    if (t < nblk) partial[t] = t ? s[t - 1] : 0;   // exclusive
}

__global__ void k_scan_c(const int* __restrict__ cnt, const int* __restrict__ partial,
                         int* __restrict__ row_ptr) {
    __shared__ int s[256];
    int i = blockIdx.x * 256 + threadIdx.x, t = threadIdx.x;
    int c = (i < NTOT) ? cnt[i] : 0;
    int v = c + (c & 1);                   // padded
    s[t] = v;
    __syncthreads();
    for (int off = 1; off < 256; off <<= 1) {
        int u = (t >= off) ? s[t - off] : 0;
        __syncthreads();
        s[t] += u;
        __syncthreads();
    }
    if (i < NTOT) row_ptr[i] = s[t] - v + partial[blockIdx.x];
    if (i == NTOT - 1) row_ptr[NTOT] = s[t] + partial[blockIdx.x];
}

__global__ void k_fill(EdgePtrs ep, const int* __restrict__ row_ptr,
                       int* __restrict__ cursor, int2* __restrict__ csr) {
    int eidx = blockIdx.x * blockDim.x + threadIdx.x;
    if (eidx >= ETOT) return;
    int e = 0;
    #pragma unroll
    for (int i = 1; i < 13; i++) e += (eidx >= d_EOFF[i]);
    int li = eidx - d_EOFF[e];
    const int* base = ep.p[e];
    int src = base[li], dst = base[d_ECNT[e] + li];
    int sg = d_NOFF[d_EST[e]] + src;
    int dg = d_NOFF[d_EDT[e]] + dst;
    int pos = atomicAdd(&cursor[dg], 1);
    csr[row_ptr[dg] + pos] = make_int2(sg | (d_EL[e] << 17), d_EBASE[e] + src);
}

// ---------------- kqv: q -> fp32; k,v -> separate half tables ----------------
__global__ void k_kqv(const float* __restrict__ h, const float* __restrict__ Wkqv,
                      const float* __restrict__ bkqv, float* __restrict__ qagg,
                      __half* __restrict__ ktab, __half* __restrict__ vtab, int layer) {
    int n0 = blockIdx.x * 8;
    int t = node_type(n0);          // 8-node tiles never straddle type boundaries
    __shared__ float hs[8][64];
    for (int i = threadIdx.x; i < 512; i += 192)
        hs[i >> 6][i & 63] = h[(size_t)n0 * 64 + i];
    __syncthreads();
    const float* W = Wkqv + (size_t)(layer * 3 + t) * HID * 192;
    int j = threadIdx.x;
    float b = bkqv[(layer * 3 + t) * 192 + j];
    float acc[8];
    #pragma unroll
    for (int n = 0; n < 8; n++) acc[n] = b;
    for (int i = 0; i < 64; i++) {
        float w = W[i * 192 + j];
        #pragma unroll
        for (int n = 0; n < 8; n++) acc[n] += hs[n][i] * w;
    }
    if (j < 64) {
        #pragma unroll
        for (int n = 0; n < 8; n++) ktab[(size_t)(n0 + n) * 64 + j] = __float2half(acc[n]);
    } else if (j < 128) {
        #pragma unroll
        for (int n = 0; n < 8; n++) qagg[(size_t)(n0 + n) * 64 + (j - 64)] = acc[n];
    } else {
        #pragma unroll
        for (int n = 0; n < 8; n++) vtab[(size_t)(n0 + n) * 64 + (j - 128)] = __float2half(acc[n]);
    }
}

// ---------------- qw precompute: qwtab[node][el][h*16+d] = prel*scale*sum_x q[h,x]*Wk[e,h,d,x]
__global__ __launch_bounds__(384)
void k_qw(const float* __restrict__ qbuf, const float* __restrict__ Wk,
          const float* __restrict__ prel, __half* __restrict__ qwtab, int layer) {
    int b = blockIdx.x; int t, n0, lim;
    if (b < 469)       { t = 0; n0 = b * 64;                lim = NU; }
    else if (b < 1407) { t = 1; n0 = NU + (b - 469) * 64;   lim = NU + NE_; }
    else               { t = 2; n0 = NU + NE_ + (b - 1407) * 64; lim = NTOT; }
    int el = threadIdx.x >> 6, lane = threadIdx.x & 63;
    int h = lane >> 4, d = lane & 15;
    if (t == 2 && el > 0) return;
    int e = d_ELMAP[t][el];
    const float* Wkp = Wk + (((size_t)layer * 13 + e) * 4 + h) * 256 + d * 16;
    float pr = prel[(layer * 13 + e) * 4 + h] * 0.25f;
    float wk[16];
    #pragma unroll
    for (int x = 0; x < 16; x++) wk[x] = Wkp[x] * pr;
    for (int n = 0; n < 64; n++) {
        int node = n0 + n;
        if (node >= lim) break;
        const float4* qp = (const float4*)(qbuf + (size_t)node * 64 + h * 16);
        float a = 0.f;
        #pragma unroll
        for (int c = 0; c < 4; c++) {
            float4 q4 = qp[c];
            a += q4.x * wk[c*4] + q4.y * wk[c*4+1] + q4.z * wk[c*4+2] + q4.w * wk[c*4+3];
        }
        qwtab[(size_t)node * 384 + el * 64 + lane] = __float2half(a);
    }
}

// ---------------- vt precompute: vttab[slot][h*16+xo] = sum_d v[src][h,d]*Wv[e,h,d,xo]
__global__ __launch_bounds__(512)
void k_trans(const __half* __restrict__ vtab, const float* __restrict__ Wv,
             __half* __restrict__ vttab, int layer) {
    int b = blockIdx.x;
    int e = 0;
    #pragma unroll
    for (int i = 1; i < 13; i++) e += (b >= d_TBOFF[i]);
    int s0 = d_EBASE[e] + (b - d_TBOFF[e]) * 64;
    int lim = d_EBASE[e] + d_ESLOTS[e];
    int wave = threadIdx.x >> 6, lane = threadIdx.x & 63;
    int h = lane >> 4, xo = lane & 15;
    const float* Wvp = Wv + (((size_t)layer * 13 + e) * 4 + h) * 256 + xo;
    float wv[16];
    #pragma unroll
    for (int d = 0; d < 16; d++) wv[d] = Wvp[d * 16];
    int nbase = d_NOFF[d_EST[e]] - d_EBASE[e];
    for (int k = 0; k < 8; k++) {
        int slot = s0 + wave * 8 + k;
        if (slot >= lim) break;                       // uniform within wave
        const __half2* vp = (const __half2*)(vtab + (size_t)(nbase + slot) * 64 + h * 16);
        float a = 0.f;
        #pragma unroll
        for (int d2 = 0; d2 < 8; d2++) {
            float2 vf = __half22float2(vp[d2]);
            a += vf.x * wv[2*d2] + vf.y * wv[2*d2 + 1];
        }
        vttab[(size_t)slot * 64 + lane] = __float2half(a);
    }
}

// ---------------- fused gather: score + online softmax + message agg ----------------
__global__ __launch_bounds__(512)
void k_gather(float* __restrict__ qagg, const __half* __restrict__ ktab,
              const __half* __restrict__ vttab, const __half* __restrict__ qwtab,
              const int* __restrict__ row_ptr, const int2* __restrict__ csr) {
    int wave = threadIdx.x >> 6, lane = threadIdx.x & 63;
    int node = blockIdx.x * 8 + wave;
    if (node >= NTOT) return;
    int t = node_type(node);
    const __half* qp = qwtab + (size_t)node * 384 + lane;
    float qw0 = __half2float(qp[0]);
    float qw1 = 0.f, qw2 = 0.f, qw3 = 0.f, qw4 = 0.f, qw5 = 0.f;
    if (t != 2) {
        qw1 = __half2float(qp[64]);  qw2 = __half2float(qp[128]);
        qw3 = __half2float(qp[192]); qw4 = __half2float(qp[256]);
        qw5 = __half2float(qp[320]);
    }
    int beg = row_ptr[node], end = row_ptr[node + 1];
    float m = -1e30f, l = 0.f, acc = 0.f;

    int2 cA, cB; __half kA, kB, vA, vB;
    int i = beg;
    if (i < end) {
        cA = csr[i]; cB = csr[i + 1];
        int ndA = (cA.x >= 0) ? (cA.x & 0x1FFFF) : 0, slA = (cA.x >= 0) ? cA.y : 0;
        int ndB = (cB.x >= 0) ? (cB.x & 0x1FFFF) : 0, slB = (cB.x >= 0) ? cB.y : 0;
        kA = ktab[(size_t)ndA * 64 + lane];  vA = vttab[(size_t)slA * 64 + lane];
        kB = ktab[(size_t)ndB * 64 + lane];  vB = vttab[(size_t)slB * 64 + lane];
    }
    while (i < end) {
        int2 pA = cA, pB = cB;
        __half ka = kA, va = vA, kb = kB, vb = vB;
        i += 2;
        if (i < end) {   // prefetch next pair
            cA = csr[i]; cB = csr[i + 1];
            int ndA = (cA.x >= 0) ? (cA.x & 0x1FFFF) : 0, slA = (cA.x >= 0) ? cA.y : 0;
            int ndB = (cB.x >= 0) ? (cB.x & 0x1FFFF) : 0, slB = (cB.x >= 0) ? cB.y : 0;
            kA = ktab[(size_t)ndA * 64 + lane];  vA = vttab[(size_t)slA * 64 + lane];
            kB = ktab[(size_t)ndB * 64 + lane];  vB = vttab[(size_t)slB * 64 + lane];
        }
        // ---- edge A ----
        {
            int el = (pA.x >> 17) & 7;
            float qsel = (el == 0) ? qw0 : (el == 1) ? qw1 : (el == 2) ? qw2
                       : (el == 3) ? qw3 : (el == 4) ? qw4 : qw5;
            float s = __half2float(ka) * qsel;
            s += __shfl_xor(s, 1, 64); s += __shfl_xor(s, 2, 64);
            s += __shfl_xor(s, 4, 64); s += __shfl_xor(s, 8, 64);
            bool valid = pA.x >= 0;
            s = valid ? s : -1e30f;
            float m2  = fmaxf(m, s);
            float sc1 = __expf(m - m2);
            float es  = valid ? __expf(s - m2) : 0.f;
            l   = l * sc1 + es;
            acc = acc * sc1 + es * __half2float(va);
            m = m2;
        }
        // ---- edge B ----
        {
            int el = (pB.x >> 17) & 7;
            float qsel = (el == 0) ? qw0 : (el == 1) ? qw1 : (el == 2) ? qw2
                       : (el == 3) ? qw3 : (el == 4) ? qw4 : qw5;
            float s = __half2float(kb) * qsel;
            s += __shfl_xor(s, 1, 64); s += __shfl_xor(s, 2, 64);
            s += __shfl_xor(s, 4, 64); s += __shfl_xor(s, 8, 64);
            bool valid = pB.x >= 0;
            s = valid ? s : -1e30f;
            float m2  = fmaxf(m, s);
            float sc1 = __expf(m - m2);
            float es  = valid ? __expf(s - m2) : 0.f;
            l   = l * sc1 + es;
            acc = acc * sc1 + es * __half2float(vb);
            m = m2;
        }
    }
    qagg[(size_t)node * 64 + lane] = (l > 0.f) ? acc / l : 0.f;
}

// ---------------- epilogue: gelu -> @Wout + bout -> skip-gate -> relu ----------------
__global__ __launch_bounds__(256)
void k_out(const float* __restrict__ agg, const float* __restrict__ Wout,
           const float* __restrict__ bout, const float* __restrict__ skip,
           float* __restrict__ h, int layer) {
    int b = blockIdx.x; int t, n0, lim;
    if (b < 938)       { t = 0; n0 = b * 32;                 lim = NU; }
    else if (b < 2813) { t = 1; n0 = NU + (b - 938) * 32;    lim = NU + NE_; }
    else               { t = 2; n0 = NU + NE_ + (b - 2813) * 32; lim = NTOT; }
    int nn = min(32, lim - n0);
    __shared__ float gs[32][64];
    for (int i = threadIdx.x; i < nn * 64; i += 256) {
        float o = agg[(size_t)n0 * 64 + i];
        gs[i >> 6][i & 63] = 0.5f * o * (1.f + erff(o * 0.70710678118654752f));
    }
    __syncthreads();
    int j = threadIdx.x & 63, g = threadIdx.x >> 6;   // 4 groups x 8 nodes
    const float* W = Wout + (size_t)(layer * 3 + t) * HID * HID;
    float bb = bout[(layer * 3 + t) * HID + j];
    float acc[8];
    #pragma unroll
    for (int n = 0; n < 8; n++) acc[n] = bb;
    for (int i = 0; i < 64; i++) {
        float w = W[i * 64 + j];
        #pragma unroll
        for (int n = 0; n < 8; n++) acc[n] += gs[g * 8 + n][i] * w;
    }
    float gk = 1.f / (1.f + __expf(-skip[layer * 3 + t]));
    #pragma unroll
    for (int n = 0; n < 8; n++) {
        int node = n0 + g * 8 + n;
        if (node < lim) {
            float r = gk * acc[n] + (1.f - gk) * h[(size_t)node * 64 + j];
            h[(size_t)node * 64 + j] = fmaxf(r, 0.f);
        }
    }
}

// ---------------- final l2 normalize ----------------
__global__ void k_l2(const float* __restrict__ h, float* __restrict__ out) {
    int node = blockIdx.x, j = threadIdx.x;   // 64 = one wave
    float v = h[(size_t)node * HID + j];
    float ss = v * v;
    #pragma unroll
    for (int off = 32; off > 0; off >>= 1) ss += __shfl_down(ss, off);
    ss = __shfl(ss, 0);
    float nrm = fmaxf(sqrtf(ss), 1e-12f);
    out[(size_t)node * HID + j] = v / nrm;
}

extern "C" void kernel_launch(void* const* d_in, const int* in_sizes, int n_in,
                              void* d_out, int out_size, void* d_ws, size_t ws_size,
                              hipStream_t stream) {
    const float* xu   = (const float*)d_in[0];
    const float* xe   = (const float*)d_in[1];
    const float* xv   = (const float*)d_in[2];
    const float* Wu   = (const float*)d_in[3];
    const float* bu   = (const float*)d_in[4];
    const float* We   = (const float*)d_in[5];
    const float* be   = (const float*)d_in[6];
    const float* Wv_  = (const float*)d_in[7];
    const float* bv   = (const float*)d_in[8];
    const float* embu = (const float*)d_in[9];
    const float* embe = (const float*)d_in[10];
    const float* embv = (const float*)d_in[11];
    const float* Wkqv = (const float*)d_in[12];
    const float* bkqv = (const float*)d_in[13];
    const float* Wk   = (const float*)d_in[14];
    const float* Wv   = (const float*)d_in[15];
    const float* prel = (const float*)d_in[16];
    const float* Wout = (const float*)d_in[17];
    const float* bout = (const float*)d_in[18];
    const float* skip = (const float*)d_in[19];
    const int*   idu  = (const int*)d_in[20];
    const int*   ide  = (const int*)d_in[21];
    const int*   idv  = (const int*)d_in[22];
    EdgePtrs ep;
    for (int e = 0; e < 13; e++) ep.p[e] = (const int*)d_in[23 + e];

    float* ws  = (float*)d_ws;
    float* h      = ws;                                    // NTOT*64 f32
    float* qagg   = h    + (size_t)NTOT * HID;             // NTOT*64 f32 (q, then agg)
    __half* ktab  = (__half*)(qagg + (size_t)NTOT * HID);  // NTOT*64 half
    __half* vtab  = ktab + (size_t)NTOT * HID;             // NTOT*64 half
    __half* vttab = vtab + (size_t)NTOT * HID;             // NSLOT*64 half
    __half* qwtab = vttab + (size_t)NSLOT * HID;           // NTOT*384 half
    int* cnt     = (int*)(qwtab + (size_t)NTOT * 384);     // NTOT
    int* cursor  = cnt + NTOT;                             // NTOT
    int* row_ptr = cursor + NTOT;                          // NTOT+1
    int* partial = row_ptr + NTOT + 1;                     // 512 (+pad for int2 align)
    int2* csr    = (int2*)(partial + 512 + 1);             // (ETOT+NTOT) int2

    k_init<<<(NTOT * HID + 255) / 256, 256, 0, stream>>>(
        xu, xe, xv, Wu, bu, We, be, Wv_, bv, embu, embe, embv, idu, ide, idv, h);

    // CSR build (edges are layer-invariant); rows padded to even, dummies = -1
    hipMemsetAsync(cnt, 0, (size_t)2 * NTOT * 4, stream);          // cnt + cursor
    hipMemsetAsync(csr, 0xFF, (size_t)(ETOT + NTOT) * 8, stream);  // dummy entries
    int nblk = (NTOT + 255) / 256;   // 356
    k_cnt<<<(ETOT + 255) / 256, 256, 0, stream>>>(ep, cnt);
    k_scan_a<<<nblk, 256, 0, stream>>>(cnt, partial);
    k_scan_b<<<1, 512, 0, stream>>>(partial, nblk);
    k_scan_c<<<nblk, 256, 0, stream>>>(cnt, partial, row_ptr);
    k_fill<<<(ETOT + 255) / 256, 256, 0, stream>>>(ep, row_ptr, cursor, csr);

    for (int l = 0; l < LAYERS; l++) {
        k_kqv<<<NTOT / 8, 192, 0, stream>>>(h, Wkqv, bkqv, qagg, ktab, vtab, l);
        k_trans<<<8458, 512, 0, stream>>>(vtab, Wv, vttab, l);
        k_qw<<<1423, 384, 0, stream>>>(qagg, Wk, prel, qwtab, l);
        k_gather<<<(NTOT + 7) / 8, 512, 0, stream>>>(qagg, ktab, vttab, qwtab,
                                                     row_ptr, csr);
        k_out<<<2845, 256, 0, stream>>>(qagg, Wout, bout, skip, h, l);
    }
    k_l2<<<NTOT, HID, 0, stream>>>(h, (float*)d_out);
}

// Round 6
// 915.243 us; speedup vs baseline: 8.5968x; 1.0680x over previous
//
#include <hip/hip_runtime.h>
#include <hip/hip_fp16.h>
#include <math.h>

#define HID   64
#define HEADS 4
#define DH    16
#define NU    30000
#define NE_   60000
#define NV    1000
#define NTOT  91000
#define ETOT  870000
#define NSLOT 541000
#define LAYERS 2

// Edge-type tables
__device__ const int d_EOFF[14] = {0,150000,270000,330000,370000,400000,450000,
                                   570000,630000,670000,700000,750000,810000,870000};
__device__ const int d_ECNT[13] = {150000,120000,60000,40000,30000,50000,
                                   120000,60000,40000,30000,50000,60000,60000};
__device__ const int d_EST[13]  = {0,0,0,0,0,0,1,1,1,1,1,1,2};
__device__ const int d_EDT[13]  = {0,1,1,1,1,1,0,0,0,0,0,2,1};
__device__ const int d_NOFF[3]  = {0, NU, NU + NE_};
// slot base per edge type in the kvt mega-table (src-node indexed per e)
__device__ const int d_EBASE[13] = {0,30000,60000,90000,120000,150000,
                                    180000,240000,300000,360000,420000,480000,540000};
__device__ const int d_ESLOTS[13] = {30000,30000,30000,30000,30000,30000,
                                     60000,60000,60000,60000,60000,60000,1000};
// k_trans 64-slot block offsets per e: 6x469, 6x938, 1x16
__device__ const int d_TBOFF[14] = {0,469,938,1407,1876,2345,2814,
                                    3752,4690,5628,6566,7504,8442,8458};

struct EdgePtrs { const int* p[13]; };

__device__ __forceinline__ int node_type(int n) {
    return (n >= NU) + (n >= NU + NE_);
}

// ---------------- input projection: h = x@W + b + emb[ids] ----------------
__global__ void k_init(const float* __restrict__ xu, const float* __restrict__ xe,
                       const float* __restrict__ xv,
                       const float* __restrict__ Wu, const float* __restrict__ bu,
                       const float* __restrict__ We, const float* __restrict__ be,
                       const float* __restrict__ Wv_, const float* __restrict__ bv,
                       const float* __restrict__ embu, const float* __restrict__ embe,
                       const float* __restrict__ embv,
                       const int* __restrict__ idu, const int* __restrict__ ide,
                       const int* __restrict__ idv,
                       float* __restrict__ h) {
    int gid = blockIdx.x * blockDim.x + threadIdx.x;
    if (gid >= NTOT * HID) return;
    int node = gid >> 6, j = gid & 63;
    const float *x, *W, *b, *emb; const int* ids; int in_dim, n;
    if (node < NU)            { n = node;           x = xu; W = Wu;  b = bu; emb = embu; ids = idu; in_dim = 32; }
    else if (node < NU + NE_) { n = node - NU;      x = xe; W = We;  b = be; emb = embe; ids = ide; in_dim = 32; }
    else                      { n = node - NU - NE_;x = xv; W = Wv_; b = bv; emb = embv; ids = idv; in_dim = 16; }
    float acc = b[j] + emb[(size_t)ids[n] * HID + j];
    for (int i = 0; i < in_dim; i++) acc += x[(size_t)n * in_dim + i] * W[i * HID + j];
    h[gid] = acc;
}

// ---------------- CSR build (exact rows, entry = slot index) ----------------
__global__ void k_cnt(EdgePtrs ep, int* __restrict__ cnt) {
    int eidx = blockIdx.x * blockDim.x + threadIdx.x;
    if (eidx >= ETOT) return;
    int e = 0;
    #pragma unroll
    for (int i = 1; i < 13; i++) e += (eidx >= d_EOFF[i]);
    int li = eidx - d_EOFF[e];
    int dst = ep.p[e][d_ECNT[e] + li];
    atomicAdd(&cnt[d_NOFF[d_EDT[e]] + dst], 1);
}

__global__ void k_scan_a(const int* __restrict__ cnt, int* __restrict__ partial) {
    __shared__ int s[256];
    int i = blockIdx.x * 256 + threadIdx.x;
    s[threadIdx.x] = (i < NTOT) ? cnt[i] : 0;
    __syncthreads();
    for (int off = 128; off > 0; off >>= 1) {
        if (threadIdx.x < off) s[threadIdx.x] += s[threadIdx.x + off];
        __syncthreads();
    }
    if (threadIdx.x == 0) partial[blockIdx.x] = s[0];
}

__global__ void k_scan_b(int* __restrict__ partial, int nblk) {
    __shared__ int s[512];
    int t = threadIdx.x;
    s[t] = (t < nblk) ? partial[t] : 0;
    __syncthreads();
    for (int off = 1; off < 512; off <<= 1) {
        int v = (t >= off) ? s[t - off] : 0;
        __syncthreads();
        s[t] += v;
        __syncthreads();
    }
    if (t < nblk) partial[t] = t ? s[t - 1] : 0;   // exclusive
}

__global__ void k_scan_c(const int* __restrict__ cnt, const int* __restrict__ partial,
                         int* __restrict__ row_ptr) {
    __shared__ int s[256];
    int i = blockIdx.x * 256 + threadIdx.x, t = threadIdx.x;
    int v = (i < NTOT) ? cnt[i] : 0;
    s[t] = v;
    __syncthreads();
    for (int off = 1; off < 256; off <<= 1) {
        int u = (t >= off) ? s[t - off] : 0;
        __syncthreads();
        s[t] += u;
        __syncthreads();
    }
    if (i < NTOT) row_ptr[i] = s[t] - v + partial[blockIdx.x];
    if (i == NTOT - 1) row_ptr[NTOT] = s[t] + partial[blockIdx.x];
}

__global__ void k_fill(EdgePtrs ep, const int* __restrict__ row_ptr,
                       int* __restrict__ cursor, int* __restrict__ csr) {
    int eidx = blockIdx.x * blockDim.x + threadIdx.x;
    if (eidx >= ETOT) return;
    int e = 0;
    #pragma unroll
    for (int i = 1; i < 13; i++) e += (eidx >= d_EOFF[i]);
    int li = eidx - d_EOFF[e];
    const int* base = ep.p[e];
    int src = base[li], dst = base[d_ECNT[e] + li];
    int dg = d_NOFF[d_EDT[e]] + dst;
    int pos = atomicAdd(&cursor[dg], 1);
    csr[row_ptr[dg] + pos] = d_EBASE[e] + src;
}

// ---------------- kqv: q -> fp32; k,v -> half tables ----------------
__global__ void k_kqv(const float* __restrict__ h, const float* __restrict__ Wkqv,
                      const float* __restrict__ bkqv, float* __restrict__ qagg,
                      __half* __restrict__ ktab, __half* __restrict__ vtab, int layer) {
    int n0 = blockIdx.x * 8;
    int t = node_type(n0);          // 8-node tiles never straddle type boundaries
    __shared__ float hs[8][64];
    for (int i = threadIdx.x; i < 512; i += 192)
        hs[i >> 6][i & 63] = h[(size_t)n0 * 64 + i];
    __syncthreads();
    const float* W = Wkqv + (size_t)(layer * 3 + t) * HID * 192;
    int j = threadIdx.x;
    float b = bkqv[(layer * 3 + t) * 192 + j];
    float acc[8];
    #pragma unroll
    for (int n = 0; n < 8; n++) acc[n] = b;
    for (int i = 0; i < 64; i++) {
        float w = W[i * 192 + j];
        #pragma unroll
        for (int n = 0; n < 8; n++) acc[n] += hs[n][i] * w;
    }
    if (j < 64) {
        #pragma unroll
        for (int n = 0; n < 8; n++) ktab[(size_t)(n0 + n) * 64 + j] = __float2half(acc[n]);
    } else if (j < 128) {
        #pragma unroll
        for (int n = 0; n < 8; n++) qagg[(size_t)(n0 + n) * 64 + (j - 64)] = acc[n];
    } else {
        #pragma unroll
        for (int n = 0; n < 8; n++) vtab[(size_t)(n0 + n) * 64 + (j - 128)] = __float2half(acc[n]);
    }
}

// ---- trans: kvt[slot][h*16+x] = half2( prel*scale*sum_d k[h,d]Wk[e,h,d,x],
//                                        sum_d v[h,d]Wv[e,h,d,x] )
__global__ __launch_bounds__(512)
void k_trans(const __half* __restrict__ ktab, const __half* __restrict__ vtab,
             const float* __restrict__ Wk, const float* __restrict__ Wv,
             const float* __restrict__ prel, __half2* __restrict__ kvt, int layer) {
    int b = blockIdx.x;
    int e = 0;
    #pragma unroll
    for (int i = 1; i < 13; i++) e += (b >= d_TBOFF[i]);
    int s0 = d_EBASE[e] + (b - d_TBOFF[e]) * 64;
    int lim = d_EBASE[e] + d_ESLOTS[e];
    int wave = threadIdx.x >> 6, lane = threadIdx.x & 63;
    int h = lane >> 4, xo = lane & 15;
    const float* Wkp = Wk + (((size_t)layer * 13 + e) * 4 + h) * 256 + xo;
    const float* Wvp = Wv + (((size_t)layer * 13 + e) * 4 + h) * 256 + xo;
    float pr = prel[(layer * 13 + e) * 4 + h] * 0.25f;
    float wk[16], wv[16];
    #pragma unroll
    for (int d = 0; d < 16; d++) { wk[d] = Wkp[d * 16] * pr; wv[d] = Wvp[d * 16]; }
    int nbase = d_NOFF[d_EST[e]] - d_EBASE[e];
    for (int k = 0; k < 8; k++) {
        int slot = s0 + wave * 8 + k;
        if (slot >= lim) break;                     // uniform across wave
        const __half2* kp = (const __half2*)(ktab + (size_t)(nbase + slot) * 64 + h * 16);
        const __half2* vp = (const __half2*)(vtab + (size_t)(nbase + slot) * 64 + h * 16);
        float kt = 0.f, vt = 0.f;
        #pragma unroll
        for (int d2 = 0; d2 < 8; d2++) {
            float2 kf = __half22float2(kp[d2]);
            float2 vf = __half22float2(vp[d2]);
            kt += kf.x * wk[2 * d2] + kf.y * wk[2 * d2 + 1];
            vt += vf.x * wv[2 * d2] + vf.y * wv[2 * d2 + 1];
        }
        kvt[(size_t)slot * 64 + lane] = __float22half2_rn(make_float2(kt, vt));
    }
}

// ---------------- fused gather: score + online softmax + message agg ----------------
__global__ __launch_bounds__(512)
void k_gather(float* __restrict__ qagg, const __half2* __restrict__ kvt,
              const int* __restrict__ row_ptr, const int* __restrict__ csr) {
    int wave = threadIdx.x >> 6, lane = threadIdx.x & 63;
    int node = blockIdx.x * 8 + wave;
    if (node >= NTOT) return;
    float q = qagg[(size_t)node * 64 + lane];   // q[h][x]
    int beg = row_ptr[node], end = row_ptr[node + 1];
    float m = -1e30f, l = 0.f, acc = 0.f;
    for (int base = beg; base < end; base += 64) {
        int n = end - base; if (n > 64) n = 64;
        int ent = csr[base + ((lane < n) ? lane : 0)];   // 64 entries in one load
        for (int c = 0; c < n; c += 8) {
            int cn = n - c; if (cn > 8) cn = 8;
            __half2 f[8];
            #pragma unroll
            for (int k = 0; k < 8; k++) {               // batch 8 gathers (MLP)
                int idx = c + ((k < cn) ? k : 0);
                int sl = __shfl(ent, idx, 64);
                f[k] = kvt[(size_t)sl * 64 + lane];
            }
            #pragma unroll
            for (int k = 0; k < 8; k++) {
                if (k >= cn) break;
                float2 kv2 = __half22float2(f[k]);
                float s = q * kv2.x;
                s += __shfl_xor(s, 1, 64); s += __shfl_xor(s, 2, 64);
                s += __shfl_xor(s, 4, 64); s += __shfl_xor(s, 8, 64);
                float d2 = s - m;
                float t = __expf(-fabsf(d2));   // one exp per edge
                bool pos = d2 > 0.f;
                m = fmaxf(m, s);
                float sc1 = pos ? t : 1.f;
                float es  = pos ? 1.f : t;
                l   = l * sc1 + es;
                acc = acc * sc1 + es * kv2.y;
            }
        }
    }
    qagg[(size_t)node * 64 + lane] = (l > 0.f) ? acc / l : 0.f;
}

// ---------------- epilogue: gelu -> @Wout + bout -> skip-gate -> relu ----------------
__global__ __launch_bounds__(256)
void k_out(const float* __restrict__ agg, const float* __restrict__ Wout,
           const float* __restrict__ bout, const float* __restrict__ skip,
           float* __restrict__ h, int layer) {
    int b = blockIdx.x; int t, n0, lim;
    if (b < 938)       { t = 0; n0 = b * 32;                 lim = NU; }
    else if (b < 2813) { t = 1; n0 = NU + (b - 938) * 32;    lim = NU + NE_; }
    else               { t = 2; n0 = NU + NE_ + (b - 2813) * 32; lim = NTOT; }
    int nn = min(32, lim - n0);
    __shared__ float gs[32][64];
    for (int i = threadIdx.x; i < nn * 64; i += 256) {
        float o = agg[(size_t)n0 * 64 + i];
        gs[i >> 6][i & 63] = 0.5f * o * (1.f + erff(o * 0.70710678118654752f));
    }
    __syncthreads();
    int j = threadIdx.x & 63, g = threadIdx.x >> 6;   // 4 groups x 8 nodes
    const float* W = Wout + (size_t)(layer * 3 + t) * HID * HID;
    float bb = bout[(layer * 3 + t) * HID + j];
    float acc[8];
    #pragma unroll
    for (int n = 0; n < 8; n++) acc[n] = bb;
    for (int i = 0; i < 64; i++) {
        float w = W[i * 64 + j];
        #pragma unroll
        for (int n = 0; n < 8; n++) acc[n] += gs[g * 8 + n][i] * w;
    }
    float gk = 1.f / (1.f + __expf(-skip[layer * 3 + t]));
    #pragma unroll
    for (int n = 0; n < 8; n++) {
        int node = n0 + g * 8 + n;
        if (node < lim) {
            float r = gk * acc[n] + (1.f - gk) * h[(size_t)node * 64 + j];
            h[(size_t)node * 64 + j] = fmaxf(r, 0.f);
        }
    }
}

// ---------------- final l2 normalize ----------------
__global__ void k_l2(const float* __restrict__ h, float* __restrict__ out) {
    int node = blockIdx.x, j = threadIdx.x;   // 64 = one wave
    float v = h[(size_t)node * HID + j];
    float ss = v * v;
    #pragma unroll
    for (int off = 32; off > 0; off >>= 1) ss += __shfl_down(ss, off);
    ss = __shfl(ss, 0);
    float nrm = fmaxf(sqrtf(ss), 1e-12f);
    out[(size_t)node * HID + j] = v / nrm;
}

extern "C" void kernel_launch(void* const* d_in, const int* in_sizes, int n_in,
                              void* d_out, int out_size, void* d_ws, size_t ws_size,
                              hipStream_t stream) {
    const float* xu   = (const float*)d_in[0];
    const float* xe   = (const float*)d_in[1];
    const float* xv   = (const float*)d_in[2];
    const float* Wu   = (const float*)d_in[3];
    const float* bu   = (const float*)d_in[4];
    const float* We   = (const float*)d_in[5];
    const float* be   = (const float*)d_in[6];
    const float* Wv_  = (const float*)d_in[7];
    const float* bv   = (const float*)d_in[8];
    const float* embu = (const float*)d_in[9];
    const float* embe = (const float*)d_in[10];
    const float* embv = (const float*)d_in[11];
    const float* Wkqv = (const float*)d_in[12];
    const float* bkqv = (const float*)d_in[13];
    const float* Wk   = (const float*)d_in[14];
    const float* Wv   = (const float*)d_in[15];
    const float* prel = (const float*)d_in[16];
    const float* Wout = (const float*)d_in[17];
    const float* bout = (const float*)d_in[18];
    const float* skip = (const float*)d_in[19];
    const int*   idu  = (const int*)d_in[20];
    const int*   ide  = (const int*)d_in[21];
    const int*   idv  = (const int*)d_in[22];
    EdgePtrs ep;
    for (int e = 0; e < 13; e++) ep.p[e] = (const int*)d_in[23 + e];

    float* ws  = (float*)d_ws;
    float* h      = ws;                                    // NTOT*64 f32
    float* qagg   = h    + (size_t)NTOT * HID;             // NTOT*64 f32 (q, then agg)
    __half* ktab  = (__half*)(qagg + (size_t)NTOT * HID);  // NTOT*64 half
    __half* vtab  = ktab + (size_t)NTOT * HID;             // NTOT*64 half
    __half2* kvt  = (__half2*)(vtab + (size_t)NTOT * HID); // NSLOT*64 half2
    int* cnt     = (int*)(kvt + (size_t)NSLOT * HID);      // NTOT
    int* cursor  = cnt + NTOT;                             // NTOT
    int* row_ptr = cursor + NTOT;                          // NTOT+1
    int* partial = row_ptr + NTOT + 1;                     // 512
    int* csr     = partial + 512;                          // ETOT int

    k_init<<<(NTOT * HID + 255) / 256, 256, 0, stream>>>(
        xu, xe, xv, Wu, bu, We, be, Wv_, bv, embu, embe, embv, idu, ide, idv, h);

    // CSR build (edges are layer-invariant); exact rows, entry = slot id
    hipMemsetAsync(cnt, 0, (size_t)2 * NTOT * 4, stream);   // cnt + cursor
    int nblk = (NTOT + 255) / 256;   // 356
    k_cnt<<<(ETOT + 255) / 256, 256, 0, stream>>>(ep, cnt);
    k_scan_a<<<nblk, 256, 0, stream>>>(cnt, partial);
    k_scan_b<<<1, 512, 0, stream>>>(partial, nblk);
    k_scan_c<<<nblk, 256, 0, stream>>>(cnt, partial, row_ptr);
    k_fill<<<(ETOT + 255) / 256, 256, 0, stream>>>(ep, row_ptr, cursor, csr);

    for (int l = 0; l < LAYERS; l++) {
        k_kqv<<<NTOT / 8, 192, 0, stream>>>(h, Wkqv, bkqv, qagg, ktab, vtab, l);
        k_trans<<<8458, 512, 0, stream>>>(ktab, vtab, Wk, Wv, prel, kvt, l);
        k_gather<<<(NTOT + 7) / 8, 512, 0, stream>>>(qagg, kvt, row_ptr, csr);
        k_out<<<2845, 256, 0, stream>>>(qagg, Wout, bout, skip, h, l);
    }
    k_l2<<<NTOT, HID, 0, stream>>>(h, (float*)d_out);
}